// Round 6
// baseline (1073.253 us; speedup 1.0000x reference)
//
#include <hip/hip_runtime.h>

typedef unsigned short u16;
typedef unsigned int   u32;

#define B_   128
#define S_   48
#define H_   100
#define G_   400
#define PXP  1120   // px/hx row pitch in u16 elements (1116 used, padded; 2240 B = 140x16B)

__device__ __forceinline__ float b2f(u16 u) {
    union { u32 i; float f; } v; v.i = ((u32)u) << 16; return v.f;
}
__device__ __forceinline__ u16 f2b(float f) {
    union { float f; u32 i; } v; v.f = f;
    u32 r = v.i + 0x7FFF + ((v.i >> 16) & 1);
    return (u16)(r >> 16);
}

// fast, overflow-safe activation forms (v_exp based; err ~1e-6 vs libm)
__device__ __forceinline__ float fsig(float x) { return 1.f / (1.f + __expf(-x)); }
__device__ __forceinline__ float ftanh(float x) {
    const float t = __expf(-2.f * fabsf(x));   // t in (0,1], no overflow
    const float r = (1.f - t) / (1.f + t);
    return copysignf(r, x);
}

// dtype-flexible weight load: bf==1 -> bf16 storage, bf==0 -> fp32 storage
__device__ __forceinline__ float ldw(const void* p, long i, int bf) {
    return bf ? b2f(((const u16*)p)[i]) : ((const float*)p)[i];
}

// ---------------------------------------------------------------------------
// Dtype probe (proven in the passing runs).
// ---------------------------------------------------------------------------
__global__ __launch_bounds__(256) void detect_kernel(const void* wemb, int* flag)
{
    const int t = threadIdx.x;
    __shared__ int s;
    if (t == 0) s = 0;
    __syncthreads();
    int bad = 0;
    const u16* p = (const u16*)wemb;
    for (int i = t; i < 4096; i += 256) {
        float v = b2f(p[i]);
        if (!(fabsf(v) < 1e4f)) bad = 1;
    }
    if (bad) atomicOr(&s, 1);
    __syncthreads();
    if (t == 0) *flag = s ? 0 : 1;
}

// ---------------------------------------------------------------------------
// Embedding: word gather + char conv/maxpool.  grid (B, S, 2), block 64.
// ---------------------------------------------------------------------------
__global__ __launch_bounds__(64) void embed_kernel(
    const int* __restrict__ qw, const int* __restrict__ qc,
    const int* __restrict__ sw, const int* __restrict__ sc,
    const void* __restrict__ wemb, const void* __restrict__ cemb,
    const void* __restrict__ cw, const void* __restrict__ cb,
    u16* __restrict__ px, u16* __restrict__ hx, const int* __restrict__ flagp)
{
    const int bf = *flagp;
    const int b = blockIdx.x, s = blockIdx.y, seq = blockIdx.z;
    const int* words = seq ? sw : qw;
    const int* chars = seq ? sc : qc;
    u16* dst = seq ? hx : px;
    const int t = threadIdx.x;

    u16* row = dst + (long)(s * B_ + b) * PXP;
    const int w = words[b * S_ + s];
    if (bf) {
        const u32* src = (const u32*)((const u16*)wemb + (long)w * 300);
        u32* d32 = (u32*)row;
        for (int d = t; d < 150; d += 64) d32[d] = src[d];
    } else {
        const float* src = (const float*)wemb + (long)w * 300;
        for (int d = t; d < 300; d += 64) row[d] = f2b(src[d]);
    }

    __shared__ float ce[256];
    const int* ch = chars + (b * S_ + s) * 16;
    for (int j = t; j < 256; j += 64) {
        int ci = ch[j >> 4];
        ce[j] = ldw(cemb, ci * 16 + (j & 15), bf);
    }
    __syncthreads();

    float cwr[3][16], cbr[16];
#pragma unroll
    for (int oc = 0; oc < 16; ++oc) {
        cbr[oc] = ldw(cb, oc, bf);
#pragma unroll
        for (int kk = 0; kk < 3; ++kk) cwr[kk][oc] = ldw(cw, oc * 3 + kk, bf);
    }

    float vmax[16];
#pragma unroll
    for (int oc = 0; oc < 16; ++oc) vmax[oc] = -1e30f;

    for (int p = t; p < 254; p += 64) {
        float c0 = ce[p], c1 = ce[p + 1], c2 = ce[p + 2];
#pragma unroll
        for (int oc = 0; oc < 16; ++oc) {
            float v = fmaf(c0, cwr[0][oc], fmaf(c1, cwr[1][oc], fmaf(c2, cwr[2][oc], cbr[oc])));
            vmax[oc] = fmaxf(vmax[oc], v);
        }
    }
#pragma unroll
    for (int m = 32; m; m >>= 1) {
#pragma unroll
        for (int oc = 0; oc < 16; ++oc)
            vmax[oc] = fmaxf(vmax[oc], __shfl_xor(vmax[oc], m));
    }
    if (t == 0) {
#pragma unroll
        for (int oc = 0; oc < 16; ++oc) {
            float v = vmax[oc];
            if (b != 0) v = fmaxf(v, 0.f);   // ref quirk: batch row 0 skips relu
            row[300 + oc] = f2b(v);
        }
    }
}

// ---------------------------------------------------------------------------
// Xg = X @ wih^T + (bih + bhh).  grid (48, 7, 2), block 256.
// gfx950: bf16 MFMA, 128x64 tile, BK=64.  Round-5 verified structure
// (double-buffered LDS, gload_lds A staging, source-side XOR swizzle).
// Rounds 2/3: reg prefetch across barriers spills.  Round 5: counted/drained
// vmcnt variants neutral (m139-class) -- this shape is at its structural
// plateau; do not re-pipeline.
// ---------------------------------------------------------------------------
#if defined(__gfx950__)

typedef __attribute__((ext_vector_type(4))) float f32x4;
typedef __attribute__((ext_vector_type(8))) __bf16 bf16x8;
#define LDPB 72  // Bs u16 pitch; 144 B = 9x16B rows, b128 reads 16B-aligned
#define BK   64

__device__ __forceinline__ void gload_lds16(const void* g, void* l) {
    __builtin_amdgcn_global_load_lds(
        (const __attribute__((address_space(1))) u32*)g,
        (__attribute__((address_space(3))) u32*)l, 16, 0, 0);
}

__global__ __launch_bounds__(256) void gemm_wih(
    const u16* __restrict__ px, const u16* __restrict__ hx,
    float* __restrict__ Xg_p, float* __restrict__ Xg_h,
    const void* __restrict__ wih, const void* __restrict__ bih,
    const void* __restrict__ bhh, int K, const int* __restrict__ flagp)
{
    const int bf = *flagp;
    const u16* A = blockIdx.z ? hx : px;
    float* C = blockIdx.z ? Xg_h : Xg_p;
    const int m0 = blockIdx.x * 128, n0 = blockIdx.y * 64;

    __shared__ __align__(16) u16 As0[128 * 64];   // unpadded, swizzled
    __shared__ __align__(16) u16 As1[128 * 64];
    __shared__ __align__(16) u16 Bs0[64 * LDPB];  // padded
    __shared__ __align__(16) u16 Bs1[64 * LDPB];

    const int tid  = threadIdx.x;
    const int lane = tid & 63;
    const int w    = tid >> 6;        // wave 0..3
    const int fr   = lane & 15;
    const int fq   = lane >> 4;

    // B staging: row rb, 32B chunk kb
    const int rb = tid >> 2;
    const int kb = (tid & 3) * 16;
    const int nB = n0 + rb;
    const int bok = nB < G_;

    // A async staging: wave w stages rows [w*32, w*32+32) in 4 calls of 8 rows.
    const int arow = lane >> 3;                 // 0..7
    const int achk = (lane & 7) ^ arow;         // logical chunk w/ swizzle
    const u16* aLane = A + (long)(m0 + w * 32 + arow) * PXP + achk * 8;

    const u16* wp = (const u16*)wih;
    const u16* bSrc = wp + (long)nB * K + kb;   // rows 8B-aligned (K%4==0)

    f32x4 acc[2][4] = {};

    auto loadB = [&](int k0, uint2* br4) {
        if (bok) {
            const u16* bp = bSrc + k0;
#pragma unroll
            for (int i = 0; i < 4; ++i) br4[i] = *(const uint2*)(bp + i * 4);
        } else {
#pragma unroll
            for (int i = 0; i < 4; ++i) { br4[i].x = 0u; br4[i].y = 0u; }
        }
    };
    auto stageA = [&](u16* dstAs, int k0) {
#pragma unroll
        for (int c = 0; c < 4; ++c)
            gload_lds16(aLane + (long)c * 8 * PXP + k0,
                        &dstAs[(w * 32 + c * 8) * 64]);
    };
    auto writeB = [&](u16* dstBs, const uint2* br4) {
        u16* bs = &dstBs[rb * LDPB + kb];
#pragma unroll
        for (int i = 0; i < 4; ++i) *(uint2*)(bs + i * 4) = br4[i];
    };
    auto compute = [&](const u16* As_, const u16* Bs_) {
#pragma unroll
        for (int ks = 0; ks < BK; ks += 32) {
            const int sw = (((ks >> 3) + fq) ^ (fr & 7)) * 8;  // swizzled read
            bf16x8 a0 = *(const bf16x8*)&As_[(w * 32 + fr) * 64 + sw];
            bf16x8 a1 = *(const bf16x8*)&As_[(w * 32 + 16 + fr) * 64 + sw];
#pragma unroll
            for (int j = 0; j < 4; ++j) {
                bf16x8 bj = *(const bf16x8*)&Bs_[(j * 16 + fr) * LDPB + ks + fq * 8];
                acc[0][j] = __builtin_amdgcn_mfma_f32_16x16x32_bf16(a0, bj, acc[0][j], 0, 0, 0);
                acc[1][j] = __builtin_amdgcn_mfma_f32_16x16x32_bf16(a1, bj, acc[1][j], 0, 0, 0);
            }
        }
    };

    const int nfull = K / BK;    // >= 4 for every layer

    // prologue: stage tile 0 into buf0
    {
        uint2 br4[4];
        loadB(0, br4);
        stageA(As0, 0);
        writeB(Bs0, br4);
    }
    asm volatile("s_waitcnt vmcnt(0) lgkmcnt(0)" ::: "memory");
    __builtin_amdgcn_s_barrier();

    int t = 0;
    while (t < nfull) {
        // phase 0: stage t+1 -> buf1, compute buf0
        if (t + 1 < nfull) {
            uint2 br4[4];
            loadB((t + 1) * BK, br4);
            stageA(As1, (t + 1) * BK);
            writeB(Bs1, br4);
        }
        compute(As0, Bs0);
        asm volatile("s_waitcnt vmcnt(0) lgkmcnt(0)" ::: "memory");
        __builtin_amdgcn_s_barrier();
        ++t;
        if (t >= nfull) break;

        // phase 1: stage t+1 -> buf0, compute buf1
        if (t + 1 < nfull) {
            uint2 br4[4];
            loadB((t + 1) * BK, br4);
            stageA(As0, (t + 1) * BK);
            writeB(Bs0, br4);
        }
        compute(As1, Bs1);
        asm volatile("s_waitcnt vmcnt(0) lgkmcnt(0)" ::: "memory");
        __builtin_amdgcn_s_barrier();
        ++t;
    }

    // K-tail (K % 64 != 0 for every layer): scalar masked into buf0
    const int k0 = nfull * BK;
    if (k0 < K) {
        {
            const int ra = tid >> 1;               // A row 0..127
            const int ka = (tid & 1) * 32;         // half-row offset in u16
            const u16* ar = A + (long)(m0 + ra) * PXP;
            u16* bs = &Bs0[rb * LDPB + kb];
            const u16* br = wp + (long)nB * K;
#pragma unroll
            for (int i = 0; i < 32; ++i) {
                const int o = ka + i;              // logical u16 offset in row
                const int k = k0 + o;
                As0[ra * 64 + (((o >> 3) ^ (ra & 7)) * 8) + (o & 7)] =
                    (k < K) ? ar[k] : (u16)0;
            }
#pragma unroll
            for (int i = 0; i < 16; ++i) {
                const int k = k0 + kb + i;
                bs[i] = (bok && k < K) ? br[k] : (u16)0;
            }
        }
        __syncthreads();
        compute(As0, Bs0);
    }

    // D layout (m89-verified): lane holds D[row=fq*4+i][col=fr] per 16x16 tile
#pragma unroll
    for (int j = 0; j < 4; ++j) {
        const int col = n0 + j * 16 + fr;
        if (col < G_) {
            const float bias = ldw(bih, col, bf) + ldw(bhh, col, bf);
#pragma unroll
            for (int m = 0; m < 2; ++m)
#pragma unroll
                for (int i = 0; i < 4; ++i) {
                    const int row = m0 + w * 32 + m * 16 + fq * 4 + i;
                    C[(long)row * G_ + col] = acc[m][j][i] + bias;
                }
        }
    }
}
#undef LDPB
#undef BK

#else  // !__gfx950__ — vector fallback (never runs on gfx950)

__global__ __launch_bounds__(256) void gemm_wih(
    const u16* __restrict__ px, const u16* __restrict__ hx,
    float* __restrict__ Xg_p, float* __restrict__ Xg_h,
    const void* __restrict__ wih, const void* __restrict__ bih,
    const void* __restrict__ bhh, int K, const int* __restrict__ flagp)
{
    const int bf = *flagp;
    const u16* A = blockIdx.z ? hx : px;
    float* C = blockIdx.z ? Xg_h : Xg_p;

    __shared__ float As[16][64];
    __shared__ float Bs[16][64];

    const int tid = threadIdx.x;
    const int tx = tid & 15, ty = tid >> 4;
    const int m0 = blockIdx.x * 64, n0 = blockIdx.y * 64;
    const int lr = tid >> 2, lk = (tid & 3) * 4;

    float acc[4][4] = {};

    for (int k0 = 0; k0 < K; k0 += 16) {
        const u16* Ap = A + (long)(m0 + lr) * PXP + k0 + lk;
#pragma unroll
        for (int u = 0; u < 4; ++u)
            As[lk + u][lr] = (k0 + lk + u < K) ? b2f(Ap[u]) : 0.f;
        {
            const int n = n0 + lr;
#pragma unroll
            for (int u = 0; u < 4; ++u) {
                const int kk = k0 + lk + u;
                Bs[lk + u][lr] = (n < G_ && kk < K) ? ldw(wih, (long)n * K + kk, bf) : 0.f;
            }
        }
        __syncthreads();
#pragma unroll
        for (int k = 0; k < 16; ++k) {
            float a[4], bq[4];
#pragma unroll
            for (int i = 0; i < 4; ++i) a[i] = As[k][ty * 4 + i];
#pragma unroll
            for (int j = 0; j < 4; ++j) bq[j] = Bs[k][tx * 4 + j];
#pragma unroll
            for (int i = 0; i < 4; ++i)
#pragma unroll
                for (int j = 0; j < 4; ++j)
                    acc[i][j] = fmaf(a[i], bq[j], acc[i][j]);
        }
        __syncthreads();
    }

#pragma unroll
    for (int j = 0; j < 4; ++j) {
        const int col = n0 + tx * 4 + j;
        if (col < G_) {
            const float bias = ldw(bih, col, bf) + ldw(bhh, col, bf);
#pragma unroll
            for (int i = 0; i < 4; ++i)
                C[(long)(m0 + ty * 4 + i) * G_ + col] = acc[i][j] + bias;
        }
    }
}

#endif

// ---------------------------------------------------------------------------
// LSTM scan: one WG per (sample, sequence).  grid (128, 2), block 448.
// Weights held PACKED: 50 x u32 (2 bf16 each) per thread.  h broadcast moved
// OFF the VALU pipe: uniform-address ds_read_b128 (hardware broadcast, LGKM
// pipe) replaces 100 v_readlane per step -- 300 -> 200 VALU ops/step, LDS
// reads dual-issue under the FMA stream.  fp32 math identical (same fmaf
// chains, same order).
// ---------------------------------------------------------------------------
__global__ __launch_bounds__(448, 2)
void lstm_scan(
    const float* __restrict__ Xg_p, const float* __restrict__ Xg_h,
    const void* __restrict__ whh,
    float* __restrict__ p_h, float* __restrict__ h_h,
    u16* __restrict__ px, u16* __restrict__ hx, int cat_off,
    const int* __restrict__ flagp)
{
    const int bf = *flagp;
    const int b = blockIdx.x, seq = blockIdx.y;
    const float* Xg = seq ? Xg_h : Xg_p;
    float* hout = seq ? h_h : p_h;
    u16* xcat = seq ? hx : px;
    const int g = threadIdx.x;

    __shared__ __align__(16) float h_lds[128];   // h (100 used, padded)
    __shared__ float g_lds[400];                 // gate pre-activations
    __shared__ float h_hist[S_ * 104];           // h history, flushed at end

    u32 wpk[50];                             // 50 packed bf16 pairs = row g of whh
    float xg = 0.f;
    if (g < G_) {
        if (bf) {
            const u32* w2 = (const u32*)whh;           // bf16 pairs, row-major
#pragma unroll
            for (int j = 0; j < 50; ++j) wpk[j] = w2[g * 50 + j];
        } else {
            const float* wf = (const float*)whh;       // legacy fp32 path
#pragma unroll
            for (int j = 0; j < 50; ++j) {
                u32 lo = f2b(wf[(long)g * 100 + 2 * j]);
                u32 hi = f2b(wf[(long)g * 100 + 2 * j + 1]);
                wpk[j] = lo | (hi << 16);
            }
        }
#pragma unroll
        for (int j = 0; j < 50; ++j) asm volatile("" : "+v"(wpk[j]));  // pin
        xg = Xg[(long)b * G_ + g];
    }
    if (g < 128) h_lds[g] = 0.f;
    float c_reg = 0.f;
    __syncthreads();

    for (int s = 0; s < S_; ++s) {
        if (g < G_) {
            float a0 = xg, a1 = 0.f, a2 = 0.f, a3 = 0.f;
#pragma unroll
            for (int u = 0; u < 100; u += 4) {
                const float4 hv = *(const float4*)&h_lds[u];   // uniform b128 broadcast
                const u32 p0 = wpk[u >> 1], p1 = wpk[(u >> 1) + 1];
                a0 = fmaf(hv.x, __int_as_float(p0 << 16),        a0);
                a1 = fmaf(hv.y, __int_as_float(p0 & 0xFFFF0000u), a1);
                a2 = fmaf(hv.z, __int_as_float(p1 << 16),        a2);
                a3 = fmaf(hv.w, __int_as_float(p1 & 0xFFFF0000u), a3);
            }
            g_lds[g] = (a0 + a1) + (a2 + a3);
            if (s + 1 < S_) xg = Xg[(long)((s + 1) * B_ + b) * G_ + g];  // prefetch
        }
        __syncthreads();
        if (g < H_) {
            const float iv = fsig(g_lds[g]);
            const float fv = fsig(g_lds[100 + g]);
            const float gv = ftanh(g_lds[200 + g]);
            const float ov = fsig(g_lds[300 + g]);
            c_reg = fv * c_reg + iv * gv;
            const float hv = ov * ftanh(c_reg);
            h_lds[g] = hv;
            h_hist[s * 104 + g] = hv;
        }
        __syncthreads();
    }

    // coalesced flush of the whole h history
    for (int i = g; i < S_ * H_; i += 448) {
        const int s = i / H_, d = i - s * H_;
        const float hv = h_hist[s * 104 + d];
        hout[(long)(s * B_ + b) * H_ + d] = hv;
        if (cat_off >= 0) xcat[(long)(s * B_ + b) * PXP + cat_off + d] = f2b(hv);
    }
}

// ---------------------------------------------------------------------------
// Cross attention.  grid (128, 2), block 256 — blockIdx.y picks direction
// (0: row-softmax -> a_p into px, 1: col-softmax -> a_h into hx).
// ---------------------------------------------------------------------------
__global__ __launch_bounds__(256) void attn_kernel(
    const float* __restrict__ p_h, const float* __restrict__ h_h,
    u16* __restrict__ px, u16* __restrict__ hx, int off)
{
    const int b = blockIdx.x, dir = blockIdx.y, t = threadIdx.x;
    __shared__ __align__(16) float P[4800], Q[4800];
    __shared__ float A[2304], Sx[2304];

    {
        float4* P4 = (float4*)P;
        float4* Q4 = (float4*)Q;
        for (int i = t; i < 1200; i += 256) {
            const int s = i / 25, d4 = i % 25;
            P4[i] = *(const float4*)(p_h + (long)(s * B_ + b) * H_ + d4 * 4);
            Q4[i] = *(const float4*)(h_h + (long)(s * B_ + b) * H_ + d4 * 4);
        }
    }
    __syncthreads();

    for (int e = t; e < 2304; e += 256) {
        const int p = e / 48, q = e % 48;
        const float4* Pr = (const float4*)&P[p * 100];
        const float4* Qr = (const float4*)&Q[q * 100];
        float a0 = 0.f, a1 = 0.f;
#pragma unroll
        for (int j = 0; j < 25; ++j) {
            const float4 u = Pr[j], v = Qr[j];
            a0 = fmaf(u.x, v.x, a0); a1 = fmaf(u.y, v.y, a1);
            a0 = fmaf(u.z, v.z, a0); a1 = fmaf(u.w, v.w, a1);
        }
        A[e] = a0 + a1;
    }
    __syncthreads();

    if (t < 48) {
        if (dir == 0) {        // softmax over q for row t
            float m = -1e30f;
            for (int q = 0; q < 48; ++q) m = fmaxf(m, A[t * 48 + q]);
            float sum = 0.f;
            for (int q = 0; q < 48; ++q) sum += __expf(A[t * 48 + q] - m);
            const float inv = 1.f / sum;
            for (int q = 0; q < 48; ++q) Sx[t * 48 + q] = __expf(A[t * 48 + q] - m) * inv;
        } else {               // softmax over p for col t
            float m = -1e30f;
            for (int p = 0; p < 48; ++p) m = fmaxf(m, A[p * 48 + t]);
            float sum = 0.f;
            for (int p = 0; p < 48; ++p) sum += __expf(A[p * 48 + t] - m);
            const float inv = 1.f / sum;
            for (int p = 0; p < 48; ++p) Sx[p * 48 + t] = __expf(A[p * 48 + t] - m) * inv;
        }
    }
    __syncthreads();

    if (dir == 0) {
        for (int e = t; e < 4800; e += 256) {  // a_p = S @ Q
            const int p = e / 100, d = e % 100;
            float acc = 0.f;
            for (int q = 0; q < 48; ++q) acc = fmaf(Sx[p * 48 + q], Q[q * 100 + d], acc);
            px[(long)(p * B_ + b) * PXP + off + d] = f2b(acc);
        }
    } else {
        for (int e = t; e < 4800; e += 256) {  // a_h[q] = sum_p S2[p][q] * P[p]
            const int q = e / 100, d = e % 100;
            float acc = 0.f;
            for (int p = 0; p < 48; ++p) acc = fmaf(Sx[p * 48 + q], P[p * 100 + d], acc);
            hx[(long)(q * B_ + b) * PXP + off + d] = f2b(acc);
        }
    }
}

// ---------------------------------------------------------------------------
// Fused head: pool -> feats -> fcl(relu) -> last(sigmoid).  grid (128),
// block 256, one block per sample.  Replaces pool_feats + fcl_kernel +
// last_kernel (2 fewer launches, no feats/z HBM round-trip).
// ---------------------------------------------------------------------------
__global__ __launch_bounds__(256) void head_kernel(
    const float* __restrict__ p_h, const float* __restrict__ h_h,
    const void* __restrict__ fw, const void* __restrict__ fb,
    const void* __restrict__ lw, const void* __restrict__ lb,
    void* __restrict__ out, const int* __restrict__ flagp)
{
    const int bf = *flagp;
    const int b = blockIdx.x, t = threadIdx.x;
    __shared__ float fl[500];    // feats
    __shared__ float zl[800];    // fcl output
    __shared__ float red[4];

    if (t < H_) {
        float hq = -1e30f, hs = -1e30f;
        for (int s = 0; s < S_; ++s) {
            hq = fmaxf(hq, p_h[(long)(s * B_ + b) * H_ + t]);
            hs = fmaxf(hs, h_h[(long)(s * B_ + b) * H_ + t]);
        }
        fl[t]       = hq;
        fl[100 + t] = hs;
        fl[200 + t] = hs - hq;
        fl[300 + t] = hq * hs;
        fl[400 + t] = fabsf(hq - hs);
    }
    __syncthreads();

    for (int o = t; o < 800; o += 256) {
        float acc = ldw(fb, o, bf);
        const long wrow = (long)o * 500;
        for (int d = 0; d < 500; ++d) acc = fmaf(fl[d], ldw(fw, wrow + d, bf), acc);
        zl[o] = fmaxf(acc, 0.f);
    }
    __syncthreads();

    // last: 2 outputs, one per 128-thread group (2 waves each)
    {
        const int c = t >> 7;          // 0 or 1
        const int u = t & 127;
        float part = 0.f;
        for (int o = u; o < 800; o += 128)
            part = fmaf(zl[o], ldw(lw, (long)c * 800 + o, bf), part);
#pragma unroll
        for (int m = 32; m; m >>= 1) part += __shfl_xor(part, m);
        if ((t & 63) == 0) red[t >> 6] = part;   // wave partials
    }
    __syncthreads();
    if (t < 2) {
        const float acc = red[2 * t] + red[2 * t + 1] + ldw(lb, t, bf);
        const float v = 1.f / (1.f + expf(-acc));
        if (bf) ((u16*)out)[b * 2 + t] = f2b(v);
        else    ((float*)out)[b * 2 + t] = v;
    }
}

// ---------------------------------------------------------------------------
extern "C" void kernel_launch(void* const* d_in, const int* in_sizes, int n_in,
                              void* d_out, int out_size, void* d_ws, size_t ws_size,
                              hipStream_t stream)
{
    (void)in_sizes; (void)n_in; (void)out_size; (void)ws_size;

    const int* qw = (const int*)d_in[0];
    const int* qc = (const int*)d_in[1];
    const int* sw = (const int*)d_in[2];
    const int* sc = (const int*)d_in[3];
    const void* wemb = d_in[4];
    const void* cemb = d_in[5];
    const void* cw   = d_in[6];
    const void* cb   = d_in[7];
    const void* fclw = d_in[28];
    const void* fclb = d_in[29];
    const void* lw   = d_in[30];
    const void* lb   = d_in[31];

    float* ws = (float*)d_ws;
    int*  flag = (int*)ws;                               // [16] floats reserved
    u16* px   = (u16*)(ws + 16);                         // bf16 px/hx
    u16* hx   = px + (long)S_ * B_ * PXP;
    float* Xg_p = (float*)(hx + (long)S_ * B_ * PXP);
    float* Xg_h = Xg_p + (long)S_ * B_ * G_;
    float* p_h  = Xg_h + (long)S_ * B_ * G_;
    float* h_h  = p_h + (long)S_ * B_ * H_;

    detect_kernel<<<dim3(1), 256, 0, stream>>>(wemb, flag);

    embed_kernel<<<dim3(B_, S_, 2), 64, 0, stream>>>(qw, qc, sw, sc, wemb, cemb, cw, cb, px, hx, flag);

    for (int k = 0; k < 5; ++k) {
        const void* wih = d_in[8 + 4 * k];
        const void* whh = d_in[9 + 4 * k];
        const void* bih = d_in[10 + 4 * k];
        const void* bhh = d_in[11 + 4 * k];
        const int K = 316 + 200 * k;

        gemm_wih<<<dim3(48, 7, 2), 256, 0, stream>>>(px, hx, Xg_p, Xg_h, wih, bih, bhh, K, flag);

        const int cat = (k < 4) ? (K + 100) : -1;
        lstm_scan<<<dim3(B_, 2), 448, 0, stream>>>(Xg_p, Xg_h, whh, p_h, h_h, px, hx, cat, flag);

        if (k < 4)
            attn_kernel<<<dim3(B_, 2), 256, 0, stream>>>(p_h, h_h, px, hx, K);
    }

    head_kernel<<<dim3(B_), 256, 0, stream>>>(p_h, h_h, fclw, fclb, lw, lb, d_out, flag);
}

// Round 7
// 942.952 us; speedup vs baseline: 1.1382x; 1.1382x over previous
//
#include <hip/hip_runtime.h>

typedef unsigned short u16;
typedef unsigned int   u32;

#define B_   128
#define S_   48
#define H_   100
#define G_   400
#define PXP  1120   // px/hx row pitch in u16 elements (1116 used, padded; 2240 B = 140x16B)

__device__ __forceinline__ float b2f(u16 u) {
    union { u32 i; float f; } v; v.i = ((u32)u) << 16; return v.f;
}
__device__ __forceinline__ u16 f2b(float f) {
    union { float f; u32 i; } v; v.f = f;
    u32 r = v.i + 0x7FFF + ((v.i >> 16) & 1);
    return (u16)(r >> 16);
}

// fast, overflow-safe activation forms (v_exp based; err ~1e-6 vs libm)
__device__ __forceinline__ float fsig(float x) { return 1.f / (1.f + __expf(-x)); }
__device__ __forceinline__ float ftanh(float x) {
    const float t = __expf(-2.f * fabsf(x));   // t in (0,1], no overflow
    const float r = (1.f - t) / (1.f + t);
    return copysignf(r, x);
}

// dtype-flexible weight load: bf==1 -> bf16 storage, bf==0 -> fp32 storage
__device__ __forceinline__ float ldw(const void* p, long i, int bf) {
    return bf ? b2f(((const u16*)p)[i]) : ((const float*)p)[i];
}

// ---------------------------------------------------------------------------
// Dtype probe (proven in the passing runs).
// ---------------------------------------------------------------------------
__global__ __launch_bounds__(256) void detect_kernel(const void* wemb, int* flag)
{
    const int t = threadIdx.x;
    __shared__ int s;
    if (t == 0) s = 0;
    __syncthreads();
    int bad = 0;
    const u16* p = (const u16*)wemb;
    for (int i = t; i < 4096; i += 256) {
        float v = b2f(p[i]);
        if (!(fabsf(v) < 1e4f)) bad = 1;
    }
    if (bad) atomicOr(&s, 1);
    __syncthreads();
    if (t == 0) *flag = s ? 0 : 1;
}

// ---------------------------------------------------------------------------
// Embedding: word gather + char conv/maxpool.  grid (B, S, 2), block 64.
// ---------------------------------------------------------------------------
__global__ __launch_bounds__(64) void embed_kernel(
    const int* __restrict__ qw, const int* __restrict__ qc,
    const int* __restrict__ sw, const int* __restrict__ sc,
    const void* __restrict__ wemb, const void* __restrict__ cemb,
    const void* __restrict__ cw, const void* __restrict__ cb,
    u16* __restrict__ px, u16* __restrict__ hx, const int* __restrict__ flagp)
{
    const int bf = *flagp;
    const int b = blockIdx.x, s = blockIdx.y, seq = blockIdx.z;
    const int* words = seq ? sw : qw;
    const int* chars = seq ? sc : qc;
    u16* dst = seq ? hx : px;
    const int t = threadIdx.x;

    u16* row = dst + (long)(s * B_ + b) * PXP;
    const int w = words[b * S_ + s];
    if (bf) {
        const u32* src = (const u32*)((const u16*)wemb + (long)w * 300);
        u32* d32 = (u32*)row;
        for (int d = t; d < 150; d += 64) d32[d] = src[d];
    } else {
        const float* src = (const float*)wemb + (long)w * 300;
        for (int d = t; d < 300; d += 64) row[d] = f2b(src[d]);
    }

    __shared__ float ce[256];
    const int* ch = chars + (b * S_ + s) * 16;
    for (int j = t; j < 256; j += 64) {
        int ci = ch[j >> 4];
        ce[j] = ldw(cemb, ci * 16 + (j & 15), bf);
    }
    __syncthreads();

    float cwr[3][16], cbr[16];
#pragma unroll
    for (int oc = 0; oc < 16; ++oc) {
        cbr[oc] = ldw(cb, oc, bf);
#pragma unroll
        for (int kk = 0; kk < 3; ++kk) cwr[kk][oc] = ldw(cw, oc * 3 + kk, bf);
    }

    float vmax[16];
#pragma unroll
    for (int oc = 0; oc < 16; ++oc) vmax[oc] = -1e30f;

    for (int p = t; p < 254; p += 64) {
        float c0 = ce[p], c1 = ce[p + 1], c2 = ce[p + 2];
#pragma unroll
        for (int oc = 0; oc < 16; ++oc) {
            float v = fmaf(c0, cwr[0][oc], fmaf(c1, cwr[1][oc], fmaf(c2, cwr[2][oc], cbr[oc])));
            vmax[oc] = fmaxf(vmax[oc], v);
        }
    }
#pragma unroll
    for (int m = 32; m; m >>= 1) {
#pragma unroll
        for (int oc = 0; oc < 16; ++oc)
            vmax[oc] = fmaxf(vmax[oc], __shfl_xor(vmax[oc], m));
    }
    if (t == 0) {
#pragma unroll
        for (int oc = 0; oc < 16; ++oc) {
            float v = vmax[oc];
            if (b != 0) v = fmaxf(v, 0.f);   // ref quirk: batch row 0 skips relu
            row[300 + oc] = f2b(v);
        }
    }
}

// ---------------------------------------------------------------------------
// Xg = X @ wih^T + (bih + bhh).  grid (48, 7, 2), block 256.
// gfx950: bf16 MFMA, 128x64 tile, BK=64.  Round-5 verified structure
// (double-buffered LDS, gload_lds A staging, source-side XOR swizzle).
// Rounds 2/3: reg prefetch across barriers spills.  Round 5: counted/drained
// vmcnt variants neutral (m139-class) -- this shape is at its structural
// plateau; do not re-pipeline.
// ---------------------------------------------------------------------------
#if defined(__gfx950__)

typedef __attribute__((ext_vector_type(4))) float f32x4;
typedef __attribute__((ext_vector_type(8))) __bf16 bf16x8;
#define LDPB 72  // Bs u16 pitch; 144 B = 9x16B rows, b128 reads 16B-aligned
#define BK   64

__device__ __forceinline__ void gload_lds16(const void* g, void* l) {
    __builtin_amdgcn_global_load_lds(
        (const __attribute__((address_space(1))) u32*)g,
        (__attribute__((address_space(3))) u32*)l, 16, 0, 0);
}

__global__ __launch_bounds__(256) void gemm_wih(
    const u16* __restrict__ px, const u16* __restrict__ hx,
    float* __restrict__ Xg_p, float* __restrict__ Xg_h,
    const void* __restrict__ wih, const void* __restrict__ bih,
    const void* __restrict__ bhh, int K, const int* __restrict__ flagp)
{
    const int bf = *flagp;
    const u16* A = blockIdx.z ? hx : px;
    float* C = blockIdx.z ? Xg_h : Xg_p;
    const int m0 = blockIdx.x * 128, n0 = blockIdx.y * 64;

    __shared__ __align__(16) u16 As0[128 * 64];   // unpadded, swizzled
    __shared__ __align__(16) u16 As1[128 * 64];
    __shared__ __align__(16) u16 Bs0[64 * LDPB];  // padded
    __shared__ __align__(16) u16 Bs1[64 * LDPB];

    const int tid  = threadIdx.x;
    const int lane = tid & 63;
    const int w    = tid >> 6;        // wave 0..3
    const int fr   = lane & 15;
    const int fq   = lane >> 4;

    // B staging: row rb, 32B chunk kb
    const int rb = tid >> 2;
    const int kb = (tid & 3) * 16;
    const int nB = n0 + rb;
    const int bok = nB < G_;

    // A async staging: wave w stages rows [w*32, w*32+32) in 4 calls of 8 rows.
    const int arow = lane >> 3;                 // 0..7
    const int achk = (lane & 7) ^ arow;         // logical chunk w/ swizzle
    const u16* aLane = A + (long)(m0 + w * 32 + arow) * PXP + achk * 8;

    const u16* wp = (const u16*)wih;
    const u16* bSrc = wp + (long)nB * K + kb;   // rows 8B-aligned (K%4==0)

    f32x4 acc[2][4] = {};

    auto loadB = [&](int k0, uint2* br4) {
        if (bok) {
            const u16* bp = bSrc + k0;
#pragma unroll
            for (int i = 0; i < 4; ++i) br4[i] = *(const uint2*)(bp + i * 4);
        } else {
#pragma unroll
            for (int i = 0; i < 4; ++i) { br4[i].x = 0u; br4[i].y = 0u; }
        }
    };
    auto stageA = [&](u16* dstAs, int k0) {
#pragma unroll
        for (int c = 0; c < 4; ++c)
            gload_lds16(aLane + (long)c * 8 * PXP + k0,
                        &dstAs[(w * 32 + c * 8) * 64]);
    };
    auto writeB = [&](u16* dstBs, const uint2* br4) {
        u16* bs = &dstBs[rb * LDPB + kb];
#pragma unroll
        for (int i = 0; i < 4; ++i) *(uint2*)(bs + i * 4) = br4[i];
    };
    auto compute = [&](const u16* As_, const u16* Bs_) {
#pragma unroll
        for (int ks = 0; ks < BK; ks += 32) {
            const int sw = (((ks >> 3) + fq) ^ (fr & 7)) * 8;  // swizzled read
            bf16x8 a0 = *(const bf16x8*)&As_[(w * 32 + fr) * 64 + sw];
            bf16x8 a1 = *(const bf16x8*)&As_[(w * 32 + 16 + fr) * 64 + sw];
#pragma unroll
            for (int j = 0; j < 4; ++j) {
                bf16x8 bj = *(const bf16x8*)&Bs_[(j * 16 + fr) * LDPB + ks + fq * 8];
                acc[0][j] = __builtin_amdgcn_mfma_f32_16x16x32_bf16(a0, bj, acc[0][j], 0, 0, 0);
                acc[1][j] = __builtin_amdgcn_mfma_f32_16x16x32_bf16(a1, bj, acc[1][j], 0, 0, 0);
            }
        }
    };

    const int nfull = K / BK;    // >= 4 for every layer

    // prologue: stage tile 0 into buf0
    {
        uint2 br4[4];
        loadB(0, br4);
        stageA(As0, 0);
        writeB(Bs0, br4);
    }
    asm volatile("s_waitcnt vmcnt(0) lgkmcnt(0)" ::: "memory");
    __builtin_amdgcn_s_barrier();

    int t = 0;
    while (t < nfull) {
        // phase 0: stage t+1 -> buf1, compute buf0
        if (t + 1 < nfull) {
            uint2 br4[4];
            loadB((t + 1) * BK, br4);
            stageA(As1, (t + 1) * BK);
            writeB(Bs1, br4);
        }
        compute(As0, Bs0);
        asm volatile("s_waitcnt vmcnt(0) lgkmcnt(0)" ::: "memory");
        __builtin_amdgcn_s_barrier();
        ++t;
        if (t >= nfull) break;

        // phase 1: stage t+1 -> buf0, compute buf1
        if (t + 1 < nfull) {
            uint2 br4[4];
            loadB((t + 1) * BK, br4);
            stageA(As0, (t + 1) * BK);
            writeB(Bs0, br4);
        }
        compute(As1, Bs1);
        asm volatile("s_waitcnt vmcnt(0) lgkmcnt(0)" ::: "memory");
        __builtin_amdgcn_s_barrier();
        ++t;
    }

    // K-tail (K % 64 != 0 for every layer): scalar masked into buf0
    const int k0 = nfull * BK;
    if (k0 < K) {
        {
            const int ra = tid >> 1;               // A row 0..127
            const int ka = (tid & 1) * 32;         // half-row offset in u16
            const u16* ar = A + (long)(m0 + ra) * PXP;
            u16* bs = &Bs0[rb * LDPB + kb];
            const u16* br = wp + (long)nB * K;
#pragma unroll
            for (int i = 0; i < 32; ++i) {
                const int o = ka + i;              // logical u16 offset in row
                const int k = k0 + o;
                As0[ra * 64 + (((o >> 3) ^ (ra & 7)) * 8) + (o & 7)] =
                    (k < K) ? ar[k] : (u16)0;
            }
#pragma unroll
            for (int i = 0; i < 16; ++i) {
                const int k = k0 + kb + i;
                bs[i] = (bok && k < K) ? br[k] : (u16)0;
            }
        }
        __syncthreads();
        compute(As0, Bs0);
    }

    // D layout (m89-verified): lane holds D[row=fq*4+i][col=fr] per 16x16 tile
#pragma unroll
    for (int j = 0; j < 4; ++j) {
        const int col = n0 + j * 16 + fr;
        if (col < G_) {
            const float bias = ldw(bih, col, bf) + ldw(bhh, col, bf);
#pragma unroll
            for (int m = 0; m < 2; ++m)
#pragma unroll
                for (int i = 0; i < 4; ++i) {
                    const int row = m0 + w * 32 + m * 16 + fq * 4 + i;
                    C[(long)row * G_ + col] = acc[m][j][i] + bias;
                }
        }
    }
}
#undef LDPB
#undef BK

#else  // !__gfx950__ — vector fallback (never runs on gfx950)

__global__ __launch_bounds__(256) void gemm_wih(
    const u16* __restrict__ px, const u16* __restrict__ hx,
    float* __restrict__ Xg_p, float* __restrict__ Xg_h,
    const void* __restrict__ wih, const void* __restrict__ bih,
    const void* __restrict__ bhh, int K, const int* __restrict__ flagp)
{
    const int bf = *flagp;
    const u16* A = blockIdx.z ? hx : px;
    float* C = blockIdx.z ? Xg_h : Xg_p;

    __shared__ float As[16][64];
    __shared__ float Bs[16][64];

    const int tid = threadIdx.x;
    const int tx = tid & 15, ty = tid >> 4;
    const int m0 = blockIdx.x * 64, n0 = blockIdx.y * 64;
    const int lr = tid >> 2, lk = (tid & 3) * 4;

    float acc[4][4] = {};

    for (int k0 = 0; k0 < K; k0 += 16) {
        const u16* Ap = A + (long)(m0 + lr) * PXP + k0 + lk;
#pragma unroll
        for (int u = 0; u < 4; ++u)
            As[lk + u][lr] = (k0 + lk + u < K) ? b2f(Ap[u]) : 0.f;
        {
            const int n = n0 + lr;
#pragma unroll
            for (int u = 0; u < 4; ++u) {
                const int kk = k0 + lk + u;
                Bs[lk + u][lr] = (n < G_ && kk < K) ? ldw(wih, (long)n * K + kk, bf) : 0.f;
            }
        }
        __syncthreads();
#pragma unroll
        for (int k = 0; k < 16; ++k) {
            float a[4], bq[4];
#pragma unroll
            for (int i = 0; i < 4; ++i) a[i] = As[k][ty * 4 + i];
#pragma unroll
            for (int j = 0; j < 4; ++j) bq[j] = Bs[k][tx * 4 + j];
#pragma unroll
            for (int i = 0; i < 4; ++i)
#pragma unroll
                for (int j = 0; j < 4; ++j)
                    acc[i][j] = fmaf(a[i], bq[j], acc[i][j]);
        }
        __syncthreads();
    }

#pragma unroll
    for (int j = 0; j < 4; ++j) {
        const int col = n0 + tx * 4 + j;
        if (col < G_) {
            const float bias = ldw(bih, col, bf) + ldw(bhh, col, bf);
#pragma unroll
            for (int i = 0; i < 4; ++i)
                C[(long)(m0 + ty * 4 + i) * G_ + col] = acc[i][j] + bias;
        }
    }
}

#endif

// ---------------------------------------------------------------------------
// LSTM scan: one WG per (sample, sequence).  grid (128, 2), block 448.
// Weights held PACKED: 50 x u32 (2 bf16 each) per thread.  h broadcast via
// uniform-address ds_read_b128 (hardware broadcast, LGKM pipe) instead of
// v_readlane -- 300 -> 200 VALU ops/step.  fp32 math identical.
// ---------------------------------------------------------------------------
__global__ __launch_bounds__(448, 2)
void lstm_scan(
    const float* __restrict__ Xg_p, const float* __restrict__ Xg_h,
    const void* __restrict__ whh,
    float* __restrict__ p_h, float* __restrict__ h_h,
    u16* __restrict__ px, u16* __restrict__ hx, int cat_off,
    const int* __restrict__ flagp)
{
    const int bf = *flagp;
    const int b = blockIdx.x, seq = blockIdx.y;
    const float* Xg = seq ? Xg_h : Xg_p;
    float* hout = seq ? h_h : p_h;
    u16* xcat = seq ? hx : px;
    const int g = threadIdx.x;

    __shared__ __align__(16) float h_lds[128];   // h (100 used, padded)
    __shared__ float g_lds[400];                 // gate pre-activations
    __shared__ float h_hist[S_ * 104];           // h history, flushed at end

    u32 wpk[50];                             // 50 packed bf16 pairs = row g of whh
    float xg = 0.f;
    if (g < G_) {
        if (bf) {
            const u32* w2 = (const u32*)whh;           // bf16 pairs, row-major
#pragma unroll
            for (int j = 0; j < 50; ++j) wpk[j] = w2[g * 50 + j];
        } else {
            const float* wf = (const float*)whh;       // legacy fp32 path
#pragma unroll
            for (int j = 0; j < 50; ++j) {
                u32 lo = f2b(wf[(long)g * 100 + 2 * j]);
                u32 hi = f2b(wf[(long)g * 100 + 2 * j + 1]);
                wpk[j] = lo | (hi << 16);
            }
        }
#pragma unroll
        for (int j = 0; j < 50; ++j) asm volatile("" : "+v"(wpk[j]));  // pin
        xg = Xg[(long)b * G_ + g];
    }
    if (g < 128) h_lds[g] = 0.f;
    float c_reg = 0.f;
    __syncthreads();

    for (int s = 0; s < S_; ++s) {
        if (g < G_) {
            float a0 = xg, a1 = 0.f, a2 = 0.f, a3 = 0.f;
#pragma unroll
            for (int u = 0; u < 100; u += 4) {
                const float4 hv = *(const float4*)&h_lds[u];   // uniform b128 broadcast
                const u32 p0 = wpk[u >> 1], p1 = wpk[(u >> 1) + 1];
                a0 = fmaf(hv.x, __int_as_float(p0 << 16),        a0);
                a1 = fmaf(hv.y, __int_as_float(p0 & 0xFFFF0000u), a1);
                a2 = fmaf(hv.z, __int_as_float(p1 << 16),        a2);
                a3 = fmaf(hv.w, __int_as_float(p1 & 0xFFFF0000u), a3);
            }
            g_lds[g] = (a0 + a1) + (a2 + a3);
            if (s + 1 < S_) xg = Xg[(long)((s + 1) * B_ + b) * G_ + g];  // prefetch
        }
        __syncthreads();
        if (g < H_) {
            const float iv = fsig(g_lds[g]);
            const float fv = fsig(g_lds[100 + g]);
            const float gv = ftanh(g_lds[200 + g]);
            const float ov = fsig(g_lds[300 + g]);
            c_reg = fv * c_reg + iv * gv;
            const float hv = ov * ftanh(c_reg);
            h_lds[g] = hv;
            h_hist[s * 104 + g] = hv;
        }
        __syncthreads();
    }

    // coalesced flush of the whole h history
    for (int i = g; i < S_ * H_; i += 448) {
        const int s = i / H_, d = i - s * H_;
        const float hv = h_hist[s * 104 + d];
        hout[(long)(s * B_ + b) * H_ + d] = hv;
        if (cat_off >= 0) xcat[(long)(s * B_ + b) * PXP + cat_off + d] = f2b(hv);
    }
}

// ---------------------------------------------------------------------------
// Cross attention.  grid (128, 2), block 256 — blockIdx.y picks direction
// (0: row-softmax -> a_p into px, 1: col-softmax -> a_h into hx).
// ---------------------------------------------------------------------------
__global__ __launch_bounds__(256) void attn_kernel(
    const float* __restrict__ p_h, const float* __restrict__ h_h,
    u16* __restrict__ px, u16* __restrict__ hx, int off)
{
    const int b = blockIdx.x, dir = blockIdx.y, t = threadIdx.x;
    __shared__ __align__(16) float P[4800], Q[4800];
    __shared__ float A[2304], Sx[2304];

    {
        float4* P4 = (float4*)P;
        float4* Q4 = (float4*)Q;
        for (int i = t; i < 1200; i += 256) {
            const int s = i / 25, d4 = i % 25;
            P4[i] = *(const float4*)(p_h + (long)(s * B_ + b) * H_ + d4 * 4);
            Q4[i] = *(const float4*)(h_h + (long)(s * B_ + b) * H_ + d4 * 4);
        }
    }
    __syncthreads();

    for (int e = t; e < 2304; e += 256) {
        const int p = e / 48, q = e % 48;
        const float4* Pr = (const float4*)&P[p * 100];
        const float4* Qr = (const float4*)&Q[q * 100];
        float a0 = 0.f, a1 = 0.f;
#pragma unroll
        for (int j = 0; j < 25; ++j) {
            const float4 u = Pr[j], v = Qr[j];
            a0 = fmaf(u.x, v.x, a0); a1 = fmaf(u.y, v.y, a1);
            a0 = fmaf(u.z, v.z, a0); a1 = fmaf(u.w, v.w, a1);
        }
        A[e] = a0 + a1;
    }
    __syncthreads();

    if (t < 48) {
        if (dir == 0) {        // softmax over q for row t
            float m = -1e30f;
            for (int q = 0; q < 48; ++q) m = fmaxf(m, A[t * 48 + q]);
            float sum = 0.f;
            for (int q = 0; q < 48; ++q) sum += __expf(A[t * 48 + q] - m);
            const float inv = 1.f / sum;
            for (int q = 0; q < 48; ++q) Sx[t * 48 + q] = __expf(A[t * 48 + q] - m) * inv;
        } else {               // softmax over p for col t
            float m = -1e30f;
            for (int p = 0; p < 48; ++p) m = fmaxf(m, A[p * 48 + t]);
            float sum = 0.f;
            for (int p = 0; p < 48; ++p) sum += __expf(A[p * 48 + t] - m);
            const float inv = 1.f / sum;
            for (int p = 0; p < 48; ++p) Sx[p * 48 + t] = __expf(A[p * 48 + t] - m) * inv;
        }
    }
    __syncthreads();

    if (dir == 0) {
        for (int e = t; e < 4800; e += 256) {  // a_p = S @ Q
            const int p = e / 100, d = e % 100;
            float acc = 0.f;
            for (int q = 0; q < 48; ++q) acc = fmaf(Sx[p * 48 + q], Q[q * 100 + d], acc);
            px[(long)(p * B_ + b) * PXP + off + d] = f2b(acc);
        }
    } else {
        for (int e = t; e < 4800; e += 256) {  // a_h[q] = sum_p S2[p][q] * P[p]
            const int q = e / 100, d = e % 100;
            float acc = 0.f;
            for (int p = 0; p < 48; ++p) acc = fmaf(Sx[p * 48 + q], P[p * 100 + d], acc);
            hx[(long)(q * B_ + b) * PXP + off + d] = f2b(acc);
        }
    }
}

// ---------------------------------------------------------------------------
// Pool + feature build.  (Proven round-5 tail -- round 6's fused head was a
// 245 us latency-bound regression: per-block uncoalesced weight rows.)
// ---------------------------------------------------------------------------
__global__ __launch_bounds__(256) void pool_feats(
    const float* __restrict__ p_h, const float* __restrict__ h_h,
    float* __restrict__ feats)
{
    const int t = blockIdx.x * 256 + threadIdx.x;
    if (t >= B_ * H_) return;
    const int b = t / H_, u = t % H_;
    float hq = -1e30f, hs = -1e30f;
    for (int s = 0; s < S_; ++s) {
        hq = fmaxf(hq, p_h[(long)(s * B_ + b) * H_ + u]);
        hs = fmaxf(hs, h_h[(long)(s * B_ + b) * H_ + u]);
    }
    float* f = feats + b * 500;
    f[u]       = hq;
    f[100 + u] = hs;
    f[200 + u] = hs - hq;
    f[300 + u] = hq * hs;
    f[400 + u] = fabsf(hq - hs);
}

// ---------------------------------------------------------------------------
// z = relu(feats @ fcl_w^T + fcl_b).
// ---------------------------------------------------------------------------
__global__ __launch_bounds__(256) void fcl_kernel(
    const float* __restrict__ feats, const void* __restrict__ fw,
    const void* __restrict__ fb, float* __restrict__ z, const int* __restrict__ flagp)
{
    const int bf = *flagp;
    const int t = blockIdx.x * 256 + threadIdx.x;
    const int o = t >> 7, b = t & 127;
    float acc = ldw(fb, o, bf);
    const float* f = feats + b * 500;
    for (int d = 0; d < 500; ++d) acc = fmaf(f[d], ldw(fw, (long)o * 500 + d, bf), acc);
    z[b * 800 + o] = fmaxf(acc, 0.f);
}

// ---------------------------------------------------------------------------
// out = sigmoid(z @ last_w^T + last_b).  Output dtype follows flag.
// ---------------------------------------------------------------------------
__global__ __launch_bounds__(256) void last_kernel(
    const float* __restrict__ z, const void* __restrict__ lw,
    const void* __restrict__ lb, void* __restrict__ out, const int* __restrict__ flagp)
{
    const int bf = *flagp;
    const int t = threadIdx.x;
    const int b = t >> 1, c = t & 1;
    float acc = ldw(lb, c, bf);
    const float* zr = z + b * 800;
    for (int o = 0; o < 800; ++o) acc = fmaf(zr[o], ldw(lw, (long)c * 800 + o, bf), acc);
    const float v = 1.f / (1.f + expf(-acc));
    if (bf) ((u16*)out)[t] = f2b(v);
    else    ((float*)out)[t] = v;
}

// ---------------------------------------------------------------------------
extern "C" void kernel_launch(void* const* d_in, const int* in_sizes, int n_in,
                              void* d_out, int out_size, void* d_ws, size_t ws_size,
                              hipStream_t stream)
{
    (void)in_sizes; (void)n_in; (void)out_size; (void)ws_size;

    const int* qw = (const int*)d_in[0];
    const int* qc = (const int*)d_in[1];
    const int* sw = (const int*)d_in[2];
    const int* sc = (const int*)d_in[3];
    const void* wemb = d_in[4];
    const void* cemb = d_in[5];
    const void* cw   = d_in[6];
    const void* cb   = d_in[7];
    const void* fclw = d_in[28];
    const void* fclb = d_in[29];
    const void* lw   = d_in[30];
    const void* lb   = d_in[31];

    float* ws = (float*)d_ws;
    int*  flag = (int*)ws;                               // [16] floats reserved
    u16* px   = (u16*)(ws + 16);                         // bf16 px/hx
    u16* hx   = px + (long)S_ * B_ * PXP;
    float* Xg_p = (float*)(hx + (long)S_ * B_ * PXP);
    float* Xg_h = Xg_p + (long)S_ * B_ * G_;
    float* p_h  = Xg_h + (long)S_ * B_ * G_;
    float* h_h  = p_h + (long)S_ * B_ * H_;
    float* feats = h_h + (long)S_ * B_ * H_;
    float* z    = feats + B_ * 500;

    detect_kernel<<<dim3(1), 256, 0, stream>>>(wemb, flag);

    embed_kernel<<<dim3(B_, S_, 2), 64, 0, stream>>>(qw, qc, sw, sc, wemb, cemb, cw, cb, px, hx, flag);

    for (int k = 0; k < 5; ++k) {
        const void* wih = d_in[8 + 4 * k];
        const void* whh = d_in[9 + 4 * k];
        const void* bih = d_in[10 + 4 * k];
        const void* bhh = d_in[11 + 4 * k];
        const int K = 316 + 200 * k;

        gemm_wih<<<dim3(48, 7, 2), 256, 0, stream>>>(px, hx, Xg_p, Xg_h, wih, bih, bhh, K, flag);

        const int cat = (k < 4) ? (K + 100) : -1;
        lstm_scan<<<dim3(B_, 2), 448, 0, stream>>>(Xg_p, Xg_h, whh, p_h, h_h, px, hx, cat, flag);

        if (k < 4)
            attn_kernel<<<dim3(B_, 2), 256, 0, stream>>>(p_h, h_h, px, hx, K);
    }

    pool_feats<<<dim3(50), 256, 0, stream>>>(p_h, h_h, feats);
    fcl_kernel<<<dim3(400), 256, 0, stream>>>(feats, fclw, fclb, z, flag);
    last_kernel<<<dim3(1), 256, 0, stream>>>(z, lw, lb, d_out, flag);
}

// Round 8
// 871.493 us; speedup vs baseline: 1.2315x; 1.0820x over previous
//
#include <hip/hip_runtime.h>

typedef unsigned short u16;
typedef unsigned int   u32;

#define B_   128
#define S_   48
#define H_   100
#define G_   400
#define PXP  1120   // px/hx row pitch in u16 elements (1116 used, padded; 2240 B = 140x16B)

__device__ __forceinline__ float b2f(u16 u) {
    union { u32 i; float f; } v; v.i = ((u32)u) << 16; return v.f;
}
__device__ __forceinline__ u16 f2b(float f) {
    union { float f; u32 i; } v; v.f = f;
    u32 r = v.i + 0x7FFF + ((v.i >> 16) & 1);
    return (u16)(r >> 16);
}

// fast, overflow-safe activation forms (v_exp based; err ~1e-6 vs libm)
__device__ __forceinline__ float fsig(float x) { return 1.f / (1.f + __expf(-x)); }
__device__ __forceinline__ float ftanh(float x) {
    const float t = __expf(-2.f * fabsf(x));   // t in (0,1], no overflow
    const float r = (1.f - t) / (1.f + t);
    return copysignf(r, x);
}

// wave-uniform broadcast of h[u] held across two per-lane registers
__device__ __forceinline__ float rl(float v0, float v1, int u) {
    return __int_as_float(
        u < 64 ? __builtin_amdgcn_readlane(__float_as_int(v0), u)
               : __builtin_amdgcn_readlane(__float_as_int(v1), u - 64));
}

// dtype-flexible weight load: bf==1 -> bf16 storage, bf==0 -> fp32 storage
__device__ __forceinline__ float ldw(const void* p, long i, int bf) {
    return bf ? b2f(((const u16*)p)[i]) : ((const float*)p)[i];
}

// ---------------------------------------------------------------------------
// Dtype probe (proven in the passing runs).
// ---------------------------------------------------------------------------
__global__ __launch_bounds__(256) void detect_kernel(const void* wemb, int* flag)
{
    const int t = threadIdx.x;
    __shared__ int s;
    if (t == 0) s = 0;
    __syncthreads();
    int bad = 0;
    const u16* p = (const u16*)wemb;
    for (int i = t; i < 4096; i += 256) {
        float v = b2f(p[i]);
        if (!(fabsf(v) < 1e4f)) bad = 1;
    }
    if (bad) atomicOr(&s, 1);
    __syncthreads();
    if (t == 0) *flag = s ? 0 : 1;
}

// ---------------------------------------------------------------------------
// Embedding: word gather + char conv/maxpool.  grid (B, S, 2), block 64.
// ---------------------------------------------------------------------------
__global__ __launch_bounds__(64) void embed_kernel(
    const int* __restrict__ qw, const int* __restrict__ qc,
    const int* __restrict__ sw, const int* __restrict__ sc,
    const void* __restrict__ wemb, const void* __restrict__ cemb,
    const void* __restrict__ cw, const void* __restrict__ cb,
    u16* __restrict__ px, u16* __restrict__ hx, const int* __restrict__ flagp)
{
    const int bf = *flagp;
    const int b = blockIdx.x, s = blockIdx.y, seq = blockIdx.z;
    const int* words = seq ? sw : qw;
    const int* chars = seq ? sc : qc;
    u16* dst = seq ? hx : px;
    const int t = threadIdx.x;

    u16* row = dst + (long)(s * B_ + b) * PXP;
    const int w = words[b * S_ + s];
    if (bf) {
        const u32* src = (const u32*)((const u16*)wemb + (long)w * 300);
        u32* d32 = (u32*)row;
        for (int d = t; d < 150; d += 64) d32[d] = src[d];
    } else {
        const float* src = (const float*)wemb + (long)w * 300;
        for (int d = t; d < 300; d += 64) row[d] = f2b(src[d]);
    }

    __shared__ float ce[256];
    const int* ch = chars + (b * S_ + s) * 16;
    for (int j = t; j < 256; j += 64) {
        int ci = ch[j >> 4];
        ce[j] = ldw(cemb, ci * 16 + (j & 15), bf);
    }
    __syncthreads();

    float cwr[3][16], cbr[16];
#pragma unroll
    for (int oc = 0; oc < 16; ++oc) {
        cbr[oc] = ldw(cb, oc, bf);
#pragma unroll
        for (int kk = 0; kk < 3; ++kk) cwr[kk][oc] = ldw(cw, oc * 3 + kk, bf);
    }

    float vmax[16];
#pragma unroll
    for (int oc = 0; oc < 16; ++oc) vmax[oc] = -1e30f;

    for (int p = t; p < 254; p += 64) {
        float c0 = ce[p], c1 = ce[p + 1], c2 = ce[p + 2];
#pragma unroll
        for (int oc = 0; oc < 16; ++oc) {
            float v = fmaf(c0, cwr[0][oc], fmaf(c1, cwr[1][oc], fmaf(c2, cwr[2][oc], cbr[oc])));
            vmax[oc] = fmaxf(vmax[oc], v);
        }
    }
#pragma unroll
    for (int m = 32; m; m >>= 1) {
#pragma unroll
        for (int oc = 0; oc < 16; ++oc)
            vmax[oc] = fmaxf(vmax[oc], __shfl_xor(vmax[oc], m));
    }
    if (t == 0) {
#pragma unroll
        for (int oc = 0; oc < 16; ++oc) {
            float v = vmax[oc];
            if (b != 0) v = fmaxf(v, 0.f);   // ref quirk: batch row 0 skips relu
            row[300 + oc] = f2b(v);
        }
    }
}

// ---------------------------------------------------------------------------
// Xg = X @ wih^T + (bih + bhh).  grid (48, 7, 2), block 256.
// gfx950: bf16 MFMA, 128x64 tile, BK=64.  Round-5 verified structure
// (double-buffered LDS, gload_lds A staging, source-side XOR swizzle).
// Rounds 2/3: reg prefetch across barriers spills.  Round 5: counted/drained
// vmcnt variants neutral (m139-class) -- this shape is at its structural
// plateau; do not re-pipeline.
// ---------------------------------------------------------------------------
#if defined(__gfx950__)

typedef __attribute__((ext_vector_type(4))) float f32x4;
typedef __attribute__((ext_vector_type(8))) __bf16 bf16x8;
#define LDPB 72  // Bs u16 pitch; 144 B = 9x16B rows, b128 reads 16B-aligned
#define BK   64

__device__ __forceinline__ void gload_lds16(const void* g, void* l) {
    __builtin_amdgcn_global_load_lds(
        (const __attribute__((address_space(1))) u32*)g,
        (__attribute__((address_space(3))) u32*)l, 16, 0, 0);
}

__global__ __launch_bounds__(256) void gemm_wih(
    const u16* __restrict__ px, const u16* __restrict__ hx,
    float* __restrict__ Xg_p, float* __restrict__ Xg_h,
    const void* __restrict__ wih, const void* __restrict__ bih,
    const void* __restrict__ bhh, int K, const int* __restrict__ flagp)
{
    const int bf = *flagp;
    const u16* A = blockIdx.z ? hx : px;
    float* C = blockIdx.z ? Xg_h : Xg_p;
    const int m0 = blockIdx.x * 128, n0 = blockIdx.y * 64;

    __shared__ __align__(16) u16 As0[128 * 64];   // unpadded, swizzled
    __shared__ __align__(16) u16 As1[128 * 64];
    __shared__ __align__(16) u16 Bs0[64 * LDPB];  // padded
    __shared__ __align__(16) u16 Bs1[64 * LDPB];

    const int tid  = threadIdx.x;
    const int lane = tid & 63;
    const int w    = tid >> 6;        // wave 0..3
    const int fr   = lane & 15;
    const int fq   = lane >> 4;

    // B staging: row rb, 32B chunk kb
    const int rb = tid >> 2;
    const int kb = (tid & 3) * 16;
    const int nB = n0 + rb;
    const int bok = nB < G_;

    // A async staging: wave w stages rows [w*32, w*32+32) in 4 calls of 8 rows.
    const int arow = lane >> 3;                 // 0..7
    const int achk = (lane & 7) ^ arow;         // logical chunk w/ swizzle
    const u16* aLane = A + (long)(m0 + w * 32 + arow) * PXP + achk * 8;

    const u16* wp = (const u16*)wih;
    const u16* bSrc = wp + (long)nB * K + kb;   // rows 8B-aligned (K%4==0)

    f32x4 acc[2][4] = {};

    auto loadB = [&](int k0, uint2* br4) {
        if (bok) {
            const u16* bp = bSrc + k0;
#pragma unroll
            for (int i = 0; i < 4; ++i) br4[i] = *(const uint2*)(bp + i * 4);
        } else {
#pragma unroll
            for (int i = 0; i < 4; ++i) { br4[i].x = 0u; br4[i].y = 0u; }
        }
    };
    auto stageA = [&](u16* dstAs, int k0) {
#pragma unroll
        for (int c = 0; c < 4; ++c)
            gload_lds16(aLane + (long)c * 8 * PXP + k0,
                        &dstAs[(w * 32 + c * 8) * 64]);
    };
    auto writeB = [&](u16* dstBs, const uint2* br4) {
        u16* bs = &dstBs[rb * LDPB + kb];
#pragma unroll
        for (int i = 0; i < 4; ++i) *(uint2*)(bs + i * 4) = br4[i];
    };
    auto compute = [&](const u16* As_, const u16* Bs_) {
#pragma unroll
        for (int ks = 0; ks < BK; ks += 32) {
            const int sw = (((ks >> 3) + fq) ^ (fr & 7)) * 8;  // swizzled read
            bf16x8 a0 = *(const bf16x8*)&As_[(w * 32 + fr) * 64 + sw];
            bf16x8 a1 = *(const bf16x8*)&As_[(w * 32 + 16 + fr) * 64 + sw];
#pragma unroll
            for (int j = 0; j < 4; ++j) {
                bf16x8 bj = *(const bf16x8*)&Bs_[(j * 16 + fr) * LDPB + ks + fq * 8];
                acc[0][j] = __builtin_amdgcn_mfma_f32_16x16x32_bf16(a0, bj, acc[0][j], 0, 0, 0);
                acc[1][j] = __builtin_amdgcn_mfma_f32_16x16x32_bf16(a1, bj, acc[1][j], 0, 0, 0);
            }
        }
    };

    const int nfull = K / BK;    // >= 4 for every layer

    // prologue: stage tile 0 into buf0
    {
        uint2 br4[4];
        loadB(0, br4);
        stageA(As0, 0);
        writeB(Bs0, br4);
    }
    asm volatile("s_waitcnt vmcnt(0) lgkmcnt(0)" ::: "memory");
    __builtin_amdgcn_s_barrier();

    int t = 0;
    while (t < nfull) {
        // phase 0: stage t+1 -> buf1, compute buf0
        if (t + 1 < nfull) {
            uint2 br4[4];
            loadB((t + 1) * BK, br4);
            stageA(As1, (t + 1) * BK);
            writeB(Bs1, br4);
        }
        compute(As0, Bs0);
        asm volatile("s_waitcnt vmcnt(0) lgkmcnt(0)" ::: "memory");
        __builtin_amdgcn_s_barrier();
        ++t;
        if (t >= nfull) break;

        // phase 1: stage t+1 -> buf0, compute buf1
        if (t + 1 < nfull) {
            uint2 br4[4];
            loadB((t + 1) * BK, br4);
            stageA(As0, (t + 1) * BK);
            writeB(Bs0, br4);
        }
        compute(As1, Bs1);
        asm volatile("s_waitcnt vmcnt(0) lgkmcnt(0)" ::: "memory");
        __builtin_amdgcn_s_barrier();
        ++t;
    }

    // K-tail (K % 64 != 0 for every layer): scalar masked into buf0
    const int k0 = nfull * BK;
    if (k0 < K) {
        {
            const int ra = tid >> 1;               // A row 0..127
            const int ka = (tid & 1) * 32;         // half-row offset in u16
            const u16* ar = A + (long)(m0 + ra) * PXP;
            u16* bs = &Bs0[rb * LDPB + kb];
            const u16* br = wp + (long)nB * K;
#pragma unroll
            for (int i = 0; i < 32; ++i) {
                const int o = ka + i;              // logical u16 offset in row
                const int k = k0 + o;
                As0[ra * 64 + (((o >> 3) ^ (ra & 7)) * 8) + (o & 7)] =
                    (k < K) ? ar[k] : (u16)0;
            }
#pragma unroll
            for (int i = 0; i < 16; ++i) {
                const int k = k0 + kb + i;
                bs[i] = (bok && k < K) ? br[k] : (u16)0;
            }
        }
        __syncthreads();
        compute(As0, Bs0);
    }

    // D layout (m89-verified): lane holds D[row=fq*4+i][col=fr] per 16x16 tile
#pragma unroll
    for (int j = 0; j < 4; ++j) {
        const int col = n0 + j * 16 + fr;
        if (col < G_) {
            const float bias = ldw(bih, col, bf) + ldw(bhh, col, bf);
#pragma unroll
            for (int m = 0; m < 2; ++m)
#pragma unroll
                for (int i = 0; i < 4; ++i) {
                    const int row = m0 + w * 32 + m * 16 + fq * 4 + i;
                    C[(long)row * G_ + col] = acc[m][j][i] + bias;
                }
        }
    }
}
#undef LDPB
#undef BK

#else  // !__gfx950__ — vector fallback (never runs on gfx950)

__global__ __launch_bounds__(256) void gemm_wih(
    const u16* __restrict__ px, const u16* __restrict__ hx,
    float* __restrict__ Xg_p, float* __restrict__ Xg_h,
    const void* __restrict__ wih, const void* __restrict__ bih,
    const void* __restrict__ bhh, int K, const int* __restrict__ flagp)
{
    const int bf = *flagp;
    const u16* A = blockIdx.z ? hx : px;
    float* C = blockIdx.z ? Xg_h : Xg_p;

    __shared__ float As[16][64];
    __shared__ float Bs[16][64];

    const int tid = threadIdx.x;
    const int tx = tid & 15, ty = tid >> 4;
    const int m0 = blockIdx.x * 64, n0 = blockIdx.y * 64;
    const int lr = tid >> 2, lk = (tid & 3) * 4;

    float acc[4][4] = {};

    for (int k0 = 0; k0 < K; k0 += 16) {
        const u16* Ap = A + (long)(m0 + lr) * PXP + k0 + lk;
#pragma unroll
        for (int u = 0; u < 4; ++u)
            As[lk + u][lr] = (k0 + lk + u < K) ? b2f(Ap[u]) : 0.f;
        {
            const int n = n0 + lr;
#pragma unroll
            for (int u = 0; u < 4; ++u) {
                const int kk = k0 + lk + u;
                Bs[lk + u][lr] = (n < G_ && kk < K) ? ldw(wih, (long)n * K + kk, bf) : 0.f;
            }
        }
        __syncthreads();
#pragma unroll
        for (int k = 0; k < 16; ++k) {
            float a[4], bq[4];
#pragma unroll
            for (int i = 0; i < 4; ++i) a[i] = As[k][ty * 4 + i];
#pragma unroll
            for (int j = 0; j < 4; ++j) bq[j] = Bs[k][tx * 4 + j];
#pragma unroll
            for (int i = 0; i < 4; ++i)
#pragma unroll
                for (int j = 0; j < 4; ++j)
                    acc[i][j] = fmaf(a[i], bq[j], acc[i][j]);
        }
        __syncthreads();
    }

#pragma unroll
    for (int j = 0; j < 4; ++j) {
        const int col = n0 + tx * 4 + j;
        if (col < G_) {
            const float bias = ldw(bih, col, bf) + ldw(bhh, col, bf);
#pragma unroll
            for (int i = 0; i < 4; ++i)
                C[(long)(m0 + ty * 4 + i) * G_ + col] = acc[i][j] + bias;
        }
    }
}

#endif

// ---------------------------------------------------------------------------
// LSTM scan: one WG per (sample, sequence).  grid (128, 2), block 448.
// Weights held PACKED: 50 x u32 (2 bf16 each) per thread.  h broadcast via
// v_readlane (round-5 proven; round-7's ds_read broadcast was latency-bound,
// 74 us).  Barriers are lgkmcnt-only raw s_barrier: __syncthreads' implicit
// vmcnt(0) was draining the next-step Xg prefetch every step (T4 lesson --
// never drain vmcnt in the loop); the xg use's own waitcnt covers it.
// ---------------------------------------------------------------------------
__global__ __launch_bounds__(448, 2)
void lstm_scan(
    const float* __restrict__ Xg_p, const float* __restrict__ Xg_h,
    const void* __restrict__ whh,
    float* __restrict__ p_h, float* __restrict__ h_h,
    u16* __restrict__ px, u16* __restrict__ hx, int cat_off,
    const int* __restrict__ flagp)
{
    const int bf = *flagp;
    const int b = blockIdx.x, seq = blockIdx.y;
    const float* Xg = seq ? Xg_h : Xg_p;
    float* hout = seq ? h_h : p_h;
    u16* xcat = seq ? hx : px;
    const int g = threadIdx.x;
    const int l = g & 63;

    __shared__ float h_lds[128];             // h (100 used, padded)
    __shared__ float g_lds[400];             // gate pre-activations
    __shared__ float h_hist[S_ * 104];       // h history, flushed at end

    u32 wpk[50];                             // 50 packed bf16 pairs = row g of whh
    float xg = 0.f;
    if (g < G_) {
        if (bf) {
            const u32* w2 = (const u32*)whh;           // bf16 pairs, row-major
#pragma unroll
            for (int j = 0; j < 50; ++j) wpk[j] = w2[g * 50 + j];
        } else {
            const float* wf = (const float*)whh;       // legacy fp32 path
#pragma unroll
            for (int j = 0; j < 50; ++j) {
                u32 lo = f2b(wf[(long)g * 100 + 2 * j]);
                u32 hi = f2b(wf[(long)g * 100 + 2 * j + 1]);
                wpk[j] = lo | (hi << 16);
            }
        }
#pragma unroll
        for (int j = 0; j < 50; ++j) asm volatile("" : "+v"(wpk[j]));  // pin
        xg = Xg[(long)b * G_ + g];
    }
    if (g < 128) h_lds[g] = 0.f;
    float c_reg = 0.f;
    __syncthreads();

    for (int s = 0; s < S_; ++s) {
        // per-wave copy of h (2 LDS reads), broadcast via readlane below
        const float hv0 = h_lds[l];
        const float hv1 = h_lds[l + 64];
        if (g < G_) {
            float a0 = xg, a1 = 0.f, a2 = 0.f, a3 = 0.f;
#pragma unroll
            for (int u = 0; u < 100; u += 4) {
                const u32 p0 = wpk[u >> 1], p1 = wpk[(u >> 1) + 1];
                const float w0 = __int_as_float(p0 << 16);
                const float w1 = __int_as_float(p0 & 0xFFFF0000u);
                const float w2 = __int_as_float(p1 << 16);
                const float w3 = __int_as_float(p1 & 0xFFFF0000u);
                a0 = fmaf(rl(hv0, hv1, u),     w0, a0);
                a1 = fmaf(rl(hv0, hv1, u + 1), w1, a1);
                a2 = fmaf(rl(hv0, hv1, u + 2), w2, a2);
                a3 = fmaf(rl(hv0, hv1, u + 3), w3, a3);
            }
            g_lds[g] = (a0 + a1) + (a2 + a3);
            if (s + 1 < S_) xg = Xg[(long)((s + 1) * B_ + b) * G_ + g];  // prefetch
        }
        // barrier A: only g_lds visibility needed -> lgkm-only (xg load stays
        // in flight; its use-site waitcnt covers it next step)
        asm volatile("s_waitcnt lgkmcnt(0)" ::: "memory");
        __builtin_amdgcn_s_barrier();
        if (g < H_) {
            const float iv = fsig(g_lds[g]);
            const float fv = fsig(g_lds[100 + g]);
            const float gv = ftanh(g_lds[200 + g]);
            const float ov = fsig(g_lds[300 + g]);
            c_reg = fv * c_reg + iv * gv;
            const float hv = ov * ftanh(c_reg);
            h_lds[g] = hv;
            h_hist[s * 104 + g] = hv;
        }
        // barrier B: h_lds/h_hist visibility -> lgkm-only
        asm volatile("s_waitcnt lgkmcnt(0)" ::: "memory");
        __builtin_amdgcn_s_barrier();
    }

    // coalesced flush of the whole h history
    for (int i = g; i < S_ * H_; i += 448) {
        const int s = i / H_, d = i - s * H_;
        const float hv = h_hist[s * 104 + d];
        hout[(long)(s * B_ + b) * H_ + d] = hv;
        if (cat_off >= 0) xcat[(long)(s * B_ + b) * PXP + cat_off + d] = f2b(hv);
    }
}

// ---------------------------------------------------------------------------
// Cross attention.  grid (128, 2), block 256 — blockIdx.y picks direction
// (0: row-softmax -> a_p into px, 1: col-softmax -> a_h into hx).
// ---------------------------------------------------------------------------
__global__ __launch_bounds__(256) void attn_kernel(
    const float* __restrict__ p_h, const float* __restrict__ h_h,
    u16* __restrict__ px, u16* __restrict__ hx, int off)
{
    const int b = blockIdx.x, dir = blockIdx.y, t = threadIdx.x;
    __shared__ __align__(16) float P[4800], Q[4800];
    __shared__ float A[2304], Sx[2304];

    {
        float4* P4 = (float4*)P;
        float4* Q4 = (float4*)Q;
        for (int i = t; i < 1200; i += 256) {
            const int s = i / 25, d4 = i % 25;
            P4[i] = *(const float4*)(p_h + (long)(s * B_ + b) * H_ + d4 * 4);
            Q4[i] = *(const float4*)(h_h + (long)(s * B_ + b) * H_ + d4 * 4);
        }
    }
    __syncthreads();

    for (int e = t; e < 2304; e += 256) {
        const int p = e / 48, q = e % 48;
        const float4* Pr = (const float4*)&P[p * 100];
        const float4* Qr = (const float4*)&Q[q * 100];
        float a0 = 0.f, a1 = 0.f;
#pragma unroll
        for (int j = 0; j < 25; ++j) {
            const float4 u = Pr[j], v = Qr[j];
            a0 = fmaf(u.x, v.x, a0); a1 = fmaf(u.y, v.y, a1);
            a0 = fmaf(u.z, v.z, a0); a1 = fmaf(u.w, v.w, a1);
        }
        A[e] = a0 + a1;
    }
    __syncthreads();

    if (t < 48) {
        if (dir == 0) {        // softmax over q for row t
            float m = -1e30f;
            for (int q = 0; q < 48; ++q) m = fmaxf(m, A[t * 48 + q]);
            float sum = 0.f;
            for (int q = 0; q < 48; ++q) sum += __expf(A[t * 48 + q] - m);
            const float inv = 1.f / sum;
            for (int q = 0; q < 48; ++q) Sx[t * 48 + q] = __expf(A[t * 48 + q] - m) * inv;
        } else {               // softmax over p for col t
            float m = -1e30f;
            for (int p = 0; p < 48; ++p) m = fmaxf(m, A[p * 48 + t]);
            float sum = 0.f;
            for (int p = 0; p < 48; ++p) sum += __expf(A[p * 48 + t] - m);
            const float inv = 1.f / sum;
            for (int p = 0; p < 48; ++p) Sx[p * 48 + t] = __expf(A[p * 48 + t] - m) * inv;
        }
    }
    __syncthreads();

    if (dir == 0) {
        for (int e = t; e < 4800; e += 256) {  // a_p = S @ Q
            const int p = e / 100, d = e % 100;
            float acc = 0.f;
            for (int q = 0; q < 48; ++q) acc = fmaf(Sx[p * 48 + q], Q[q * 100 + d], acc);
            px[(long)(p * B_ + b) * PXP + off + d] = f2b(acc);
        }
    } else {
        for (int e = t; e < 4800; e += 256) {  // a_h[q] = sum_p S2[p][q] * P[p]
            const int q = e / 100, d = e % 100;
            float acc = 0.f;
            for (int p = 0; p < 48; ++p) acc = fmaf(Sx[p * 48 + q], P[p * 100 + d], acc);
            hx[(long)(q * B_ + b) * PXP + off + d] = f2b(acc);
        }
    }
}

// ---------------------------------------------------------------------------
// Pool + feature build.  (Proven tail -- round 6's fused head was a 245 us
// latency-bound regression: per-block uncoalesced weight rows.)
// ---------------------------------------------------------------------------
__global__ __launch_bounds__(256) void pool_feats(
    const float* __restrict__ p_h, const float* __restrict__ h_h,
    float* __restrict__ feats)
{
    const int t = blockIdx.x * 256 + threadIdx.x;
    if (t >= B_ * H_) return;
    const int b = t / H_, u = t % H_;
    float hq = -1e30f, hs = -1e30f;
    for (int s = 0; s < S_; ++s) {
        hq = fmaxf(hq, p_h[(long)(s * B_ + b) * H_ + u]);
        hs = fmaxf(hs, h_h[(long)(s * B_ + b) * H_ + u]);
    }
    float* f = feats + b * 500;
    f[u]       = hq;
    f[100 + u] = hs;
    f[200 + u] = hs - hq;
    f[300 + u] = hq * hs;
    f[400 + u] = fabsf(hq - hs);
}

// ---------------------------------------------------------------------------
// z = relu(feats @ fcl_w^T + fcl_b).
// ---------------------------------------------------------------------------
__global__ __launch_bounds__(256) void fcl_kernel(
    const float* __restrict__ feats, const void* __restrict__ fw,
    const void* __restrict__ fb, float* __restrict__ z, const int* __restrict__ flagp)
{
    const int bf = *flagp;
    const int t = blockIdx.x * 256 + threadIdx.x;
    const int o = t >> 7, b = t & 127;
    float acc = ldw(fb, o, bf);
    const float* f = feats + b * 500;
    for (int d = 0; d < 500; ++d) acc = fmaf(f[d], ldw(fw, (long)o * 500 + d, bf), acc);
    z[b * 800 + o] = fmaxf(acc, 0.f);
}

// ---------------------------------------------------------------------------
// out = sigmoid(z @ last_w^T + last_b).  Output dtype follows flag.
// ---------------------------------------------------------------------------
__global__ __launch_bounds__(256) void last_kernel(
    const float* __restrict__ z, const void* __restrict__ lw,
    const void* __restrict__ lb, void* __restrict__ out, const int* __restrict__ flagp)
{
    const int bf = *flagp;
    const int t = threadIdx.x;
    const int b = t >> 1, c = t & 1;
    float acc = ldw(lb, c, bf);
    const float* zr = z + b * 800;
    for (int o = 0; o < 800; ++o) acc = fmaf(zr[o], ldw(lw, (long)c * 800 + o, bf), acc);
    const float v = 1.f / (1.f + expf(-acc));
    if (bf) ((u16*)out)[t] = f2b(v);
    else    ((float*)out)[t] = v;
}

// ---------------------------------------------------------------------------
extern "C" void kernel_launch(void* const* d_in, const int* in_sizes, int n_in,
                              void* d_out, int out_size, void* d_ws, size_t ws_size,
                              hipStream_t stream)
{
    (void)in_sizes; (void)n_in; (void)out_size; (void)ws_size;

    const int* qw = (const int*)d_in[0];
    const int* qc = (const int*)d_in[1];
    const int* sw = (const int*)d_in[2];
    const int* sc = (const int*)d_in[3];
    const void* wemb = d_in[4];
    const void* cemb = d_in[5];
    const void* cw   = d_in[6];
    const void* cb   = d_in[7];
    const void* fclw = d_in[28];
    const void* fclb = d_in[29];
    const void* lw   = d_in[30];
    const void* lb   = d_in[31];

    float* ws = (float*)d_ws;
    int*  flag = (int*)ws;                               // [16] floats reserved
    u16* px   = (u16*)(ws + 16);                         // bf16 px/hx
    u16* hx   = px + (long)S_ * B_ * PXP;
    float* Xg_p = (float*)(hx + (long)S_ * B_ * PXP);
    float* Xg_h = Xg_p + (long)S_ * B_ * G_;
    float* p_h  = Xg_h + (long)S_ * B_ * G_;
    float* h_h  = p_h + (long)S_ * B_ * H_;
    float* feats = h_h + (long)S_ * B_ * H_;
    float* z    = feats + B_ * 500;

    detect_kernel<<<dim3(1), 256, 0, stream>>>(wemb, flag);

    embed_kernel<<<dim3(B_, S_, 2), 64, 0, stream>>>(qw, qc, sw, sc, wemb, cemb, cw, cb, px, hx, flag);

    for (int k = 0; k < 5; ++k) {
        const void* wih = d_in[8 + 4 * k];
        const void* whh = d_in[9 + 4 * k];
        const void* bih = d_in[10 + 4 * k];
        const void* bhh = d_in[11 + 4 * k];
        const int K = 316 + 200 * k;

        gemm_wih<<<dim3(48, 7, 2), 256, 0, stream>>>(px, hx, Xg_p, Xg_h, wih, bih, bhh, K, flag);

        const int cat = (k < 4) ? (K + 100) : -1;
        lstm_scan<<<dim3(B_, 2), 448, 0, stream>>>(Xg_p, Xg_h, whh, p_h, h_h, px, hx, cat, flag);

        if (k < 4)
            attn_kernel<<<dim3(B_, 2), 256, 0, stream>>>(p_h, h_h, px, hx, K);
    }

    pool_feats<<<dim3(50), 256, 0, stream>>>(p_h, h_h, feats);
    fcl_kernel<<<dim3(400), 256, 0, stream>>>(feats, fclw, fclb, z, flag);
    last_kernel<<<dim3(1), 256, 0, stream>>>(z, lw, lb, d_out, flag);
}

// Round 9
// 852.313 us; speedup vs baseline: 1.2592x; 1.0225x over previous
//
#include <hip/hip_runtime.h>

typedef unsigned short u16;
typedef unsigned int   u32;

#define B_   128
#define S_   48
#define H_   100
#define G_   400
#define PXP  1120   // px/hx row pitch in u16 elements (1116 used, padded; 2240 B = 140x16B)

__device__ __forceinline__ float b2f(u16 u) {
    union { u32 i; float f; } v; v.i = ((u32)u) << 16; return v.f;
}
__device__ __forceinline__ u16 f2b(float f) {
    union { float f; u32 i; } v; v.f = f;
    u32 r = v.i + 0x7FFF + ((v.i >> 16) & 1);
    return (u16)(r >> 16);
}

// fast, overflow-safe activation forms (v_exp based; err ~1e-6 vs libm)
__device__ __forceinline__ float fsig(float x) { return 1.f / (1.f + __expf(-x)); }
__device__ __forceinline__ float ftanh(float x) {
    const float t = __expf(-2.f * fabsf(x));   // t in (0,1], no overflow
    const float r = (1.f - t) / (1.f + t);
    return copysignf(r, x);
}

// wave-uniform broadcast of h[u] held across two per-lane registers
__device__ __forceinline__ float rl(float v0, float v1, int u) {
    return __int_as_float(
        u < 64 ? __builtin_amdgcn_readlane(__float_as_int(v0), u)
               : __builtin_amdgcn_readlane(__float_as_int(v1), u - 64));
}

// dtype-flexible weight load: bf==1 -> bf16 storage, bf==0 -> fp32 storage
__device__ __forceinline__ float ldw(const void* p, long i, int bf) {
    return bf ? b2f(((const u16*)p)[i]) : ((const float*)p)[i];
}

// ---------------------------------------------------------------------------
// Dtype probe (proven in the passing runs).
// ---------------------------------------------------------------------------
__global__ __launch_bounds__(256) void detect_kernel(const void* wemb, int* flag)
{
    const int t = threadIdx.x;
    __shared__ int s;
    if (t == 0) s = 0;
    __syncthreads();
    int bad = 0;
    const u16* p = (const u16*)wemb;
    for (int i = t; i < 4096; i += 256) {
        float v = b2f(p[i]);
        if (!(fabsf(v) < 1e4f)) bad = 1;
    }
    if (bad) atomicOr(&s, 1);
    __syncthreads();
    if (t == 0) *flag = s ? 0 : 1;
}

// ---------------------------------------------------------------------------
// Embedding: word gather + char conv/maxpool.  grid (B, S, 2), block 64.
// ---------------------------------------------------------------------------
__global__ __launch_bounds__(64) void embed_kernel(
    const int* __restrict__ qw, const int* __restrict__ qc,
    const int* __restrict__ sw, const int* __restrict__ sc,
    const void* __restrict__ wemb, const void* __restrict__ cemb,
    const void* __restrict__ cw, const void* __restrict__ cb,
    u16* __restrict__ px, u16* __restrict__ hx, const int* __restrict__ flagp)
{
    const int bf = *flagp;
    const int b = blockIdx.x, s = blockIdx.y, seq = blockIdx.z;
    const int* words = seq ? sw : qw;
    const int* chars = seq ? sc : qc;
    u16* dst = seq ? hx : px;
    const int t = threadIdx.x;

    u16* row = dst + (long)(s * B_ + b) * PXP;
    const int w = words[b * S_ + s];
    if (bf) {
        const u32* src = (const u32*)((const u16*)wemb + (long)w * 300);
        u32* d32 = (u32*)row;
        for (int d = t; d < 150; d += 64) d32[d] = src[d];
    } else {
        const float* src = (const float*)wemb + (long)w * 300;
        for (int d = t; d < 300; d += 64) row[d] = f2b(src[d]);
    }

    __shared__ float ce[256];
    const int* ch = chars + (b * S_ + s) * 16;
    for (int j = t; j < 256; j += 64) {
        int ci = ch[j >> 4];
        ce[j] = ldw(cemb, ci * 16 + (j & 15), bf);
    }
    __syncthreads();

    float cwr[3][16], cbr[16];
#pragma unroll
    for (int oc = 0; oc < 16; ++oc) {
        cbr[oc] = ldw(cb, oc, bf);
#pragma unroll
        for (int kk = 0; kk < 3; ++kk) cwr[kk][oc] = ldw(cw, oc * 3 + kk, bf);
    }

    float vmax[16];
#pragma unroll
    for (int oc = 0; oc < 16; ++oc) vmax[oc] = -1e30f;

    for (int p = t; p < 254; p += 64) {
        float c0 = ce[p], c1 = ce[p + 1], c2 = ce[p + 2];
#pragma unroll
        for (int oc = 0; oc < 16; ++oc) {
            float v = fmaf(c0, cwr[0][oc], fmaf(c1, cwr[1][oc], fmaf(c2, cwr[2][oc], cbr[oc])));
            vmax[oc] = fmaxf(vmax[oc], v);
        }
    }
#pragma unroll
    for (int m = 32; m; m >>= 1) {
#pragma unroll
        for (int oc = 0; oc < 16; ++oc)
            vmax[oc] = fmaxf(vmax[oc], __shfl_xor(vmax[oc], m));
    }
    if (t == 0) {
#pragma unroll
        for (int oc = 0; oc < 16; ++oc) {
            float v = vmax[oc];
            if (b != 0) v = fmaxf(v, 0.f);   // ref quirk: batch row 0 skips relu
            row[300 + oc] = f2b(v);
        }
    }
}

// ---------------------------------------------------------------------------
// Xg = X @ wih^T + (bih + bhh).  grid (48, 7, 2), block 256.
// gfx950: bf16 MFMA, 128x64 tile, BK=64.  Round-5/8 verified structure
// (double-buffered LDS, gload_lds A staging, source-side XOR swizzle, one
// barrier per tile).  Round 9: K-tail staged with vector loads (A 16B groups
// map to single swizzled LDS chunks; B 8B groups) and tail MFMA limited to
// ceil(tail/32) k-steps (staging zero-fills; skipping +0.0 adds is
// bit-identical).
// ---------------------------------------------------------------------------
#if defined(__gfx950__)

typedef __attribute__((ext_vector_type(4))) float f32x4;
typedef __attribute__((ext_vector_type(8))) __bf16 bf16x8;
#define LDPB 72  // Bs u16 pitch; 144 B = 9x16B rows, b128 reads 16B-aligned
#define BK   64

__device__ __forceinline__ void gload_lds16(const void* g, void* l) {
    __builtin_amdgcn_global_load_lds(
        (const __attribute__((address_space(1))) u32*)g,
        (__attribute__((address_space(3))) u32*)l, 16, 0, 0);
}

__global__ __launch_bounds__(256) void gemm_wih(
    const u16* __restrict__ px, const u16* __restrict__ hx,
    float* __restrict__ Xg_p, float* __restrict__ Xg_h,
    const void* __restrict__ wih, const void* __restrict__ bih,
    const void* __restrict__ bhh, int K, const int* __restrict__ flagp)
{
    const int bf = *flagp;
    const u16* A = blockIdx.z ? hx : px;
    float* C = blockIdx.z ? Xg_h : Xg_p;
    const int m0 = blockIdx.x * 128, n0 = blockIdx.y * 64;

    __shared__ __align__(16) u16 As0[128 * 64];   // unpadded, swizzled
    __shared__ __align__(16) u16 As1[128 * 64];
    __shared__ __align__(16) u16 Bs0[64 * LDPB];  // padded
    __shared__ __align__(16) u16 Bs1[64 * LDPB];

    const int tid  = threadIdx.x;
    const int lane = tid & 63;
    const int w    = tid >> 6;        // wave 0..3
    const int fr   = lane & 15;
    const int fq   = lane >> 4;

    // B staging: row rb, 32B chunk kb
    const int rb = tid >> 2;
    const int kb = (tid & 3) * 16;
    const int nB = n0 + rb;
    const int bok = nB < G_;

    // A async staging: wave w stages rows [w*32, w*32+32) in 4 calls of 8 rows.
    const int arow = lane >> 3;                 // 0..7
    const int achk = (lane & 7) ^ arow;         // logical chunk w/ swizzle
    const u16* aLane = A + (long)(m0 + w * 32 + arow) * PXP + achk * 8;

    const u16* wp = (const u16*)wih;
    const u16* bSrc = wp + (long)nB * K + kb;   // rows 8B-aligned (K%4==0)

    f32x4 acc[2][4] = {};

    auto loadB = [&](int k0, uint2* br4) {
        if (bok) {
            const u16* bp = bSrc + k0;
#pragma unroll
            for (int i = 0; i < 4; ++i) br4[i] = *(const uint2*)(bp + i * 4);
        } else {
#pragma unroll
            for (int i = 0; i < 4; ++i) { br4[i].x = 0u; br4[i].y = 0u; }
        }
    };
    auto stageA = [&](u16* dstAs, int k0) {
#pragma unroll
        for (int c = 0; c < 4; ++c)
            gload_lds16(aLane + (long)c * 8 * PXP + k0,
                        &dstAs[(w * 32 + c * 8) * 64]);
    };
    auto writeB = [&](u16* dstBs, const uint2* br4) {
        u16* bs = &dstBs[rb * LDPB + kb];
#pragma unroll
        for (int i = 0; i < 4; ++i) *(uint2*)(bs + i * 4) = br4[i];
    };
    auto compute = [&](const u16* As_, const u16* Bs_) {
#pragma unroll
        for (int ks = 0; ks < BK; ks += 32) {
            const int sw = (((ks >> 3) + fq) ^ (fr & 7)) * 8;  // swizzled read
            bf16x8 a0 = *(const bf16x8*)&As_[(w * 32 + fr) * 64 + sw];
            bf16x8 a1 = *(const bf16x8*)&As_[(w * 32 + 16 + fr) * 64 + sw];
#pragma unroll
            for (int j = 0; j < 4; ++j) {
                bf16x8 bj = *(const bf16x8*)&Bs_[(j * 16 + fr) * LDPB + ks + fq * 8];
                acc[0][j] = __builtin_amdgcn_mfma_f32_16x16x32_bf16(a0, bj, acc[0][j], 0, 0, 0);
                acc[1][j] = __builtin_amdgcn_mfma_f32_16x16x32_bf16(a1, bj, acc[1][j], 0, 0, 0);
            }
        }
    };

    const int nfull = K / BK;    // >= 4 for every layer

    // prologue: stage tile 0 into buf0
    {
        uint2 br4[4];
        loadB(0, br4);
        stageA(As0, 0);
        writeB(Bs0, br4);
    }
    asm volatile("s_waitcnt vmcnt(0) lgkmcnt(0)" ::: "memory");
    __builtin_amdgcn_s_barrier();

    int t = 0;
    while (t < nfull) {
        // phase 0: stage t+1 -> buf1, compute buf0
        if (t + 1 < nfull) {
            uint2 br4[4];
            loadB((t + 1) * BK, br4);
            stageA(As1, (t + 1) * BK);
            writeB(Bs1, br4);
        }
        compute(As0, Bs0);
        asm volatile("s_waitcnt vmcnt(0) lgkmcnt(0)" ::: "memory");
        __builtin_amdgcn_s_barrier();
        ++t;
        if (t >= nfull) break;

        // phase 1: stage t+1 -> buf0, compute buf1
        if (t + 1 < nfull) {
            uint2 br4[4];
            loadB((t + 1) * BK, br4);
            stageA(As0, (t + 1) * BK);
            writeB(Bs0, br4);
        }
        compute(As1, Bs1);
        asm volatile("s_waitcnt vmcnt(0) lgkmcnt(0)" ::: "memory");
        __builtin_amdgcn_s_barrier();
        ++t;
    }

    // K-tail (K % 64 in {60,4,12,20,28}): vectorized masked staging into buf0.
    const int k0 = nfull * BK;
    if (k0 < K) {
        {
            const int ra = tid >> 1;               // A row 0..127
            const int ka = (tid & 1) * 32;         // half-row offset in u16
            const u16* ar = A + (long)(m0 + ra) * PXP;
            const u16* br = wp + (long)nB * K;
            u16* bs = &Bs0[rb * LDPB + kb];
            // A: 8-u16 groups land in single swizzled 16B LDS chunks
#pragma unroll
            for (int c = 0; c < 4; ++c) {
                const int o0 = ka + c * 8;
                u16* dst = &As0[ra * 64 + (((o0 >> 3) ^ (ra & 7)) * 8)];
                if (k0 + o0 + 8 <= K) {
                    *(float4*)dst = *(const float4*)(ar + k0 + o0);
                } else {
#pragma unroll
                    for (int i = 0; i < 8; ++i) {
                        const int k = k0 + o0 + i;
                        dst[i] = (k < K) ? ar[k] : (u16)0;
                    }
                }
            }
            // B: 4-u16 groups (rows 8B-aligned)
#pragma unroll
            for (int c = 0; c < 4; ++c) {
                const int o0 = kb + c * 4;
                if (bok && k0 + o0 + 4 <= K) {
                    *(uint2*)(bs + o0 - kb) = *(const uint2*)(br + k0 + o0);
                } else {
#pragma unroll
                    for (int i = 0; i < 4; ++i) {
                        const int k = k0 + o0 + i;
                        bs[o0 - kb + i] = (bok && k < K) ? br[k] : (u16)0;
                    }
                }
            }
        }
        __syncthreads();
        // only ceil(tail/32) k-steps: staging zero-fills, skipped steps add +0
        const int ksend = ((K - k0 + 31) & ~31);
        for (int ks = 0; ks < ksend; ks += 32) {
            const int sw = (((ks >> 3) + fq) ^ (fr & 7)) * 8;
            bf16x8 a0 = *(const bf16x8*)&As0[(w * 32 + fr) * 64 + sw];
            bf16x8 a1 = *(const bf16x8*)&As0[(w * 32 + 16 + fr) * 64 + sw];
#pragma unroll
            for (int j = 0; j < 4; ++j) {
                bf16x8 bj = *(const bf16x8*)&Bs0[(j * 16 + fr) * LDPB + ks + fq * 8];
                acc[0][j] = __builtin_amdgcn_mfma_f32_16x16x32_bf16(a0, bj, acc[0][j], 0, 0, 0);
                acc[1][j] = __builtin_amdgcn_mfma_f32_16x16x32_bf16(a1, bj, acc[1][j], 0, 0, 0);
            }
        }
    }

    // D layout (m89-verified): lane holds D[row=fq*4+i][col=fr] per 16x16 tile
#pragma unroll
    for (int j = 0; j < 4; ++j) {
        const int col = n0 + j * 16 + fr;
        if (col < G_) {
            const float bias = ldw(bih, col, bf) + ldw(bhh, col, bf);
#pragma unroll
            for (int m = 0; m < 2; ++m)
#pragma unroll
                for (int i = 0; i < 4; ++i) {
                    const int row = m0 + w * 32 + m * 16 + fq * 4 + i;
                    C[(long)row * G_ + col] = acc[m][j][i] + bias;
                }
        }
    }
}
#undef LDPB
#undef BK

#else  // !__gfx950__ — vector fallback (never runs on gfx950)

__global__ __launch_bounds__(256) void gemm_wih(
    const u16* __restrict__ px, const u16* __restrict__ hx,
    float* __restrict__ Xg_p, float* __restrict__ Xg_h,
    const void* __restrict__ wih, const void* __restrict__ bih,
    const void* __restrict__ bhh, int K, const int* __restrict__ flagp)
{
    const int bf = *flagp;
    const u16* A = blockIdx.z ? hx : px;
    float* C = blockIdx.z ? Xg_h : Xg_p;

    __shared__ float As[16][64];
    __shared__ float Bs[16][64];

    const int tid = threadIdx.x;
    const int tx = tid & 15, ty = tid >> 4;
    const int m0 = blockIdx.x * 64, n0 = blockIdx.y * 64;
    const int lr = tid >> 2, lk = (tid & 3) * 4;

    float acc[4][4] = {};

    for (int k0 = 0; k0 < K; k0 += 16) {
        const u16* Ap = A + (long)(m0 + lr) * PXP + k0 + lk;
#pragma unroll
        for (int u = 0; u < 4; ++u)
            As[lk + u][lr] = (k0 + lk + u < K) ? b2f(Ap[u]) : 0.f;
        {
            const int n = n0 + lr;
#pragma unroll
            for (int u = 0; u < 4; ++u) {
                const int kk = k0 + lk + u;
                Bs[lk + u][lr] = (n < G_ && kk < K) ? ldw(wih, (long)n * K + kk, bf) : 0.f;
            }
        }
        __syncthreads();
#pragma unroll
        for (int k = 0; k < 16; ++k) {
            float a[4], bq[4];
#pragma unroll
            for (int i = 0; i < 4; ++i) a[i] = As[k][ty * 4 + i];
#pragma unroll
            for (int j = 0; j < 4; ++j) bq[j] = Bs[k][tx * 4 + j];
#pragma unroll
            for (int i = 0; i < 4; ++i)
#pragma unroll
                for (int j = 0; j < 4; ++j)
                    acc[i][j] = fmaf(a[i], bq[j], acc[i][j]);
        }
        __syncthreads();
    }

#pragma unroll
    for (int j = 0; j < 4; ++j) {
        const int col = n0 + tx * 4 + j;
        if (col < G_) {
            const float bias = ldw(bih, col, bf) + ldw(bhh, col, bf);
#pragma unroll
            for (int i = 0; i < 4; ++i)
                C[(long)(m0 + ty * 4 + i) * G_ + col] = acc[i][j] + bias;
        }
    }
}

#endif

// ---------------------------------------------------------------------------
// LSTM scan: one WG per (sample, sequence).  grid (128, 2), block 448.
// Weights held PACKED: 50 x u32 (2 bf16 each) per thread.  h broadcast via
// v_readlane (round-5 proven; round-7's ds_read broadcast was latency-bound,
// 74 us).  Barriers are lgkmcnt-only raw s_barrier: __syncthreads' implicit
// vmcnt(0) was draining the next-step Xg prefetch every step (T4 lesson --
// never drain vmcnt in the loop); the xg use's own waitcnt covers it.
// ---------------------------------------------------------------------------
__global__ __launch_bounds__(448, 2)
void lstm_scan(
    const float* __restrict__ Xg_p, const float* __restrict__ Xg_h,
    const void* __restrict__ whh,
    float* __restrict__ p_h, float* __restrict__ h_h,
    u16* __restrict__ px, u16* __restrict__ hx, int cat_off,
    const int* __restrict__ flagp)
{
    const int bf = *flagp;
    const int b = blockIdx.x, seq = blockIdx.y;
    const float* Xg = seq ? Xg_h : Xg_p;
    float* hout = seq ? h_h : p_h;
    u16* xcat = seq ? hx : px;
    const int g = threadIdx.x;
    const int l = g & 63;

    __shared__ float h_lds[128];             // h (100 used, padded)
    __shared__ float g_lds[400];             // gate pre-activations
    __shared__ float h_hist[S_ * 104];       // h history, flushed at end

    u32 wpk[50];                             // 50 packed bf16 pairs = row g of whh
    float xg = 0.f;
    if (g < G_) {
        if (bf) {
            const u32* w2 = (const u32*)whh;           // bf16 pairs, row-major
#pragma unroll
            for (int j = 0; j < 50; ++j) wpk[j] = w2[g * 50 + j];
        } else {
            const float* wf = (const float*)whh;       // legacy fp32 path
#pragma unroll
            for (int j = 0; j < 50; ++j) {
                u32 lo = f2b(wf[(long)g * 100 + 2 * j]);
                u32 hi = f2b(wf[(long)g * 100 + 2 * j + 1]);
                wpk[j] = lo | (hi << 16);
            }
        }
#pragma unroll
        for (int j = 0; j < 50; ++j) asm volatile("" : "+v"(wpk[j]));  // pin
        xg = Xg[(long)b * G_ + g];
    }
    if (g < 128) h_lds[g] = 0.f;
    float c_reg = 0.f;
    __syncthreads();

    for (int s = 0; s < S_; ++s) {
        // per-wave copy of h (2 LDS reads), broadcast via readlane below
        const float hv0 = h_lds[l];
        const float hv1 = h_lds[l + 64];
        if (g < G_) {
            float a0 = xg, a1 = 0.f, a2 = 0.f, a3 = 0.f;
#pragma unroll
            for (int u = 0; u < 100; u += 4) {
                const u32 p0 = wpk[u >> 1], p1 = wpk[(u >> 1) + 1];
                const float w0 = __int_as_float(p0 << 16);
                const float w1 = __int_as_float(p0 & 0xFFFF0000u);
                const float w2 = __int_as_float(p1 << 16);
                const float w3 = __int_as_float(p1 & 0xFFFF0000u);
                a0 = fmaf(rl(hv0, hv1, u),     w0, a0);
                a1 = fmaf(rl(hv0, hv1, u + 1), w1, a1);
                a2 = fmaf(rl(hv0, hv1, u + 2), w2, a2);
                a3 = fmaf(rl(hv0, hv1, u + 3), w3, a3);
            }
            g_lds[g] = (a0 + a1) + (a2 + a3);
            if (s + 1 < S_) xg = Xg[(long)((s + 1) * B_ + b) * G_ + g];  // prefetch
        }
        // barrier A: only g_lds visibility needed -> lgkm-only (xg load stays
        // in flight; its use-site waitcnt covers it next step)
        asm volatile("s_waitcnt lgkmcnt(0)" ::: "memory");
        __builtin_amdgcn_s_barrier();
        if (g < H_) {
            const float iv = fsig(g_lds[g]);
            const float fv = fsig(g_lds[100 + g]);
            const float gv = ftanh(g_lds[200 + g]);
            const float ov = fsig(g_lds[300 + g]);
            c_reg = fv * c_reg + iv * gv;
            const float hv = ov * ftanh(c_reg);
            h_lds[g] = hv;
            h_hist[s * 104 + g] = hv;
        }
        // barrier B: h_lds/h_hist visibility -> lgkm-only
        asm volatile("s_waitcnt lgkmcnt(0)" ::: "memory");
        __builtin_amdgcn_s_barrier();
    }

    // coalesced flush of the whole h history
    for (int i = g; i < S_ * H_; i += 448) {
        const int s = i / H_, d = i - s * H_;
        const float hv = h_hist[s * 104 + d];
        hout[(long)(s * B_ + b) * H_ + d] = hv;
        if (cat_off >= 0) xcat[(long)(s * B_ + b) * PXP + cat_off + d] = f2b(hv);
    }
}

// ---------------------------------------------------------------------------
// Cross attention.  grid (128, 2), block 256 — blockIdx.y picks direction.
// Softmax: exp computed once (stored during sum pass, scaled in place).
// ---------------------------------------------------------------------------
__global__ __launch_bounds__(256) void attn_kernel(
    const float* __restrict__ p_h, const float* __restrict__ h_h,
    u16* __restrict__ px, u16* __restrict__ hx, int off)
{
    const int b = blockIdx.x, dir = blockIdx.y, t = threadIdx.x;
    __shared__ __align__(16) float P[4800], Q[4800];
    __shared__ float A[2304], Sx[2304];

    {
        float4* P4 = (float4*)P;
        float4* Q4 = (float4*)Q;
        for (int i = t; i < 1200; i += 256) {
            const int s = i / 25, d4 = i % 25;
            P4[i] = *(const float4*)(p_h + (long)(s * B_ + b) * H_ + d4 * 4);
            Q4[i] = *(const float4*)(h_h + (long)(s * B_ + b) * H_ + d4 * 4);
        }
    }
    __syncthreads();

    for (int e = t; e < 2304; e += 256) {
        const int p = e / 48, q = e % 48;
        const float4* Pr = (const float4*)&P[p * 100];
        const float4* Qr = (const float4*)&Q[q * 100];
        float a0 = 0.f, a1 = 0.f;
#pragma unroll
        for (int j = 0; j < 25; ++j) {
            const float4 u = Pr[j], v = Qr[j];
            a0 = fmaf(u.x, v.x, a0); a1 = fmaf(u.y, v.y, a1);
            a0 = fmaf(u.z, v.z, a0); a1 = fmaf(u.w, v.w, a1);
        }
        A[e] = a0 + a1;
    }
    __syncthreads();

    if (t < 48) {
        if (dir == 0) {        // softmax over q for row t
            float m = -1e30f;
            for (int q = 0; q < 48; ++q) m = fmaxf(m, A[t * 48 + q]);
            float sum = 0.f;
            for (int q = 0; q < 48; ++q) {
                const float e = __expf(A[t * 48 + q] - m);
                Sx[t * 48 + q] = e;
                sum += e;
            }
            const float inv = 1.f / sum;
            for (int q = 0; q < 48; ++q) Sx[t * 48 + q] *= inv;
        } else {               // softmax over p for col t
            float m = -1e30f;
            for (int p = 0; p < 48; ++p) m = fmaxf(m, A[p * 48 + t]);
            float sum = 0.f;
            for (int p = 0; p < 48; ++p) {
                const float e = __expf(A[p * 48 + t] - m);
                Sx[p * 48 + t] = e;
                sum += e;
            }
            const float inv = 1.f / sum;
            for (int p = 0; p < 48; ++p) Sx[p * 48 + t] *= inv;
        }
    }
    __syncthreads();

    if (dir == 0) {
        for (int e = t; e < 4800; e += 256) {  // a_p = S @ Q
            const int p = e / 100, d = e % 100;
            float acc = 0.f;
            for (int q = 0; q < 48; ++q) acc = fmaf(Sx[p * 48 + q], Q[q * 100 + d], acc);
            px[(long)(p * B_ + b) * PXP + off + d] = f2b(acc);
        }
    } else {
        for (int e = t; e < 4800; e += 256) {  // a_h[q] = sum_p S2[p][q] * P[p]
            const int q = e / 100, d = e % 100;
            float acc = 0.f;
            for (int p = 0; p < 48; ++p) acc = fmaf(Sx[p * 48 + q], P[p * 100 + d], acc);
            hx[(long)(q * B_ + b) * PXP + off + d] = f2b(acc);
        }
    }
}

// ---------------------------------------------------------------------------
// Pool + feature build.  (Proven tail -- round 6's fused head was a 245 us
// latency-bound regression: per-block uncoalesced weight rows.)
// ---------------------------------------------------------------------------
__global__ __launch_bounds__(256) void pool_feats(
    const float* __restrict__ p_h, const float* __restrict__ h_h,
    float* __restrict__ feats)
{
    const int t = blockIdx.x * 256 + threadIdx.x;
    if (t >= B_ * H_) return;
    const int b = t / H_, u = t % H_;
    float hq = -1e30f, hs = -1e30f;
    for (int s = 0; s < S_; ++s) {
        hq = fmaxf(hq, p_h[(long)(s * B_ + b) * H_ + u]);
        hs = fmaxf(hs, h_h[(long)(s * B_ + b) * H_ + u]);
    }
    float* f = feats + b * 500;
    f[u]       = hq;
    f[100 + u] = hs;
    f[200 + u] = hs - hq;
    f[300 + u] = hq * hs;
    f[400 + u] = fabsf(hq - hs);
}

// ---------------------------------------------------------------------------
// z = relu(feats @ fcl_w^T + fcl_b).
// ---------------------------------------------------------------------------
__global__ __launch_bounds__(256) void fcl_kernel(
    const float* __restrict__ feats, const void* __restrict__ fw,
    const void* __restrict__ fb, float* __restrict__ z, const int* __restrict__ flagp)
{
    const int bf = *flagp;
    const int t = blockIdx.x * 256 + threadIdx.x;
    const int o = t >> 7, b = t & 127;
    float acc = ldw(fb, o, bf);
    const float* f = feats + b * 500;
    for (int d = 0; d < 500; ++d) acc = fmaf(f[d], ldw(fw, (long)o * 500 + d, bf), acc);
    z[b * 800 + o] = fmaxf(acc, 0.f);
}

// ---------------------------------------------------------------------------
// out = sigmoid(z @ last_w^T + last_b).  Output dtype follows flag.
// ---------------------------------------------------------------------------
__global__ __launch_bounds__(256) void last_kernel(
    const float* __restrict__ z, const void* __restrict__ lw,
    const void* __restrict__ lb, void* __restrict__ out, const int* __restrict__ flagp)
{
    const int bf = *flagp;
    const int t = threadIdx.x;
    const int b = t >> 1, c = t & 1;
    float acc = ldw(lb, c, bf);
    const float* zr = z + b * 800;
    for (int o = 0; o < 800; ++o) acc = fmaf(zr[o], ldw(lw, (long)c * 800 + o, bf), acc);
    const float v = 1.f / (1.f + expf(-acc));
    if (bf) ((u16*)out)[t] = f2b(v);
    else    ((float*)out)[t] = v;
}

// ---------------------------------------------------------------------------
extern "C" void kernel_launch(void* const* d_in, const int* in_sizes, int n_in,
                              void* d_out, int out_size, void* d_ws, size_t ws_size,
                              hipStream_t stream)
{
    (void)in_sizes; (void)n_in; (void)out_size; (void)ws_size;

    const int* qw = (const int*)d_in[0];
    const int* qc = (const int*)d_in[1];
    const int* sw = (const int*)d_in[2];
    const int* sc = (const int*)d_in[3];
    const void* wemb = d_in[4];
    const void* cemb = d_in[5];
    const void* cw   = d_in[6];
    const void* cb   = d_in[7];
    const void* fclw = d_in[28];
    const void* fclb = d_in[29];
    const void* lw   = d_in[30];
    const void* lb   = d_in[31];

    float* ws = (float*)d_ws;
    int*  flag = (int*)ws;                               // [16] floats reserved
    u16* px   = (u16*)(ws + 16);                         // bf16 px/hx
    u16* hx   = px + (long)S_ * B_ * PXP;
    float* Xg_p = (float*)(hx + (long)S_ * B_ * PXP);
    float* Xg_h = Xg_p + (long)S_ * B_ * G_;
    float* p_h  = Xg_h + (long)S_ * B_ * G_;
    float* h_h  = p_h + (long)S_ * B_ * H_;
    float* feats = h_h + (long)S_ * B_ * H_;
    float* z    = feats + B_ * 500;

    detect_kernel<<<dim3(1), 256, 0, stream>>>(wemb, flag);

    embed_kernel<<<dim3(B_, S_, 2), 64, 0, stream>>>(qw, qc, sw, sc, wemb, cemb, cw, cb, px, hx, flag);

    for (int k = 0; k < 5; ++k) {
        const void* wih = d_in[8 + 4 * k];
        const void* whh = d_in[9 + 4 * k];
        const void* bih = d_in[10 + 4 * k];
        const void* bhh = d_in[11 + 4 * k];
        const int K = 316 + 200 * k;

        gemm_wih<<<dim3(48, 7, 2), 256, 0, stream>>>(px, hx, Xg_p, Xg_h, wih, bih, bhh, K, flag);

        const int cat = (k < 4) ? (K + 100) : -1;
        lstm_scan<<<dim3(B_, 2), 448, 0, stream>>>(Xg_p, Xg_h, whh, p_h, h_h, px, hx, cat, flag);

        if (k < 4)
            attn_kernel<<<dim3(B_, 2), 256, 0, stream>>>(p_h, h_h, px, hx, K);
    }

    pool_feats<<<dim3(50), 256, 0, stream>>>(p_h, h_h, feats);
    fcl_kernel<<<dim3(400), 256, 0, stream>>>(feats, fclw, fclb, z, flag);
    last_kernel<<<dim3(1), 256, 0, stream>>>(z, lw, lb, d_out, flag);
}

// Round 10
// 850.585 us; speedup vs baseline: 1.2618x; 1.0020x over previous
//
#include <hip/hip_runtime.h>

typedef unsigned short u16;
typedef unsigned int   u32;

#define B_   128
#define S_   48
#define H_   100
#define G_   400
#define PXP  1120   // px/hx row pitch in u16 elements (1116 used, padded; 2240 B = 140x16B)

__device__ __forceinline__ float b2f(u16 u) {
    union { u32 i; float f; } v; v.i = ((u32)u) << 16; return v.f;
}
__device__ __forceinline__ u16 f2b(float f) {
    union { float f; u32 i; } v; v.f = f;
    u32 r = v.i + 0x7FFF + ((v.i >> 16) & 1);
    return (u16)(r >> 16);
}

// fast, overflow-safe activation forms (v_exp based; err ~1e-6 vs libm)
__device__ __forceinline__ float fsig(float x) { return 1.f / (1.f + __expf(-x)); }
__device__ __forceinline__ float ftanh(float x) {
    const float t = __expf(-2.f * fabsf(x));   // t in (0,1], no overflow
    const float r = (1.f - t) / (1.f + t);
    return copysignf(r, x);
}

// wave-uniform broadcast of h[u] held across two per-lane registers
__device__ __forceinline__ float rl(float v0, float v1, int u) {
    return __int_as_float(
        u < 64 ? __builtin_amdgcn_readlane(__float_as_int(v0), u)
               : __builtin_amdgcn_readlane(__float_as_int(v1), u - 64));
}

// dtype-flexible weight load: bf==1 -> bf16 storage, bf==0 -> fp32 storage
__device__ __forceinline__ float ldw(const void* p, long i, int bf) {
    return bf ? b2f(((const u16*)p)[i]) : ((const float*)p)[i];
}

// ---------------------------------------------------------------------------
// Dtype probe (proven in the passing runs).
// ---------------------------------------------------------------------------
__global__ __launch_bounds__(256) void detect_kernel(const void* wemb, int* flag)
{
    const int t = threadIdx.x;
    __shared__ int s;
    if (t == 0) s = 0;
    __syncthreads();
    int bad = 0;
    const u16* p = (const u16*)wemb;
    for (int i = t; i < 4096; i += 256) {
        float v = b2f(p[i]);
        if (!(fabsf(v) < 1e4f)) bad = 1;
    }
    if (bad) atomicOr(&s, 1);
    __syncthreads();
    if (t == 0) *flag = s ? 0 : 1;
}

// ---------------------------------------------------------------------------
// Embedding: word gather + char conv/maxpool.  grid (B, S, 2), block 64.
// ---------------------------------------------------------------------------
__global__ __launch_bounds__(64) void embed_kernel(
    const int* __restrict__ qw, const int* __restrict__ qc,
    const int* __restrict__ sw, const int* __restrict__ sc,
    const void* __restrict__ wemb, const void* __restrict__ cemb,
    const void* __restrict__ cw, const void* __restrict__ cb,
    u16* __restrict__ px, u16* __restrict__ hx, const int* __restrict__ flagp)
{
    const int bf = *flagp;
    const int b = blockIdx.x, s = blockIdx.y, seq = blockIdx.z;
    const int* words = seq ? sw : qw;
    const int* chars = seq ? sc : qc;
    u16* dst = seq ? hx : px;
    const int t = threadIdx.x;

    u16* row = dst + (long)(s * B_ + b) * PXP;
    const int w = words[b * S_ + s];
    if (bf) {
        const u32* src = (const u32*)((const u16*)wemb + (long)w * 300);
        u32* d32 = (u32*)row;
        for (int d = t; d < 150; d += 64) d32[d] = src[d];
    } else {
        const float* src = (const float*)wemb + (long)w * 300;
        for (int d = t; d < 300; d += 64) row[d] = f2b(src[d]);
    }

    __shared__ float ce[256];
    const int* ch = chars + (b * S_ + s) * 16;
    for (int j = t; j < 256; j += 64) {
        int ci = ch[j >> 4];
        ce[j] = ldw(cemb, ci * 16 + (j & 15), bf);
    }
    __syncthreads();

    float cwr[3][16], cbr[16];
#pragma unroll
    for (int oc = 0; oc < 16; ++oc) {
        cbr[oc] = ldw(cb, oc, bf);
#pragma unroll
        for (int kk = 0; kk < 3; ++kk) cwr[kk][oc] = ldw(cw, oc * 3 + kk, bf);
    }

    float vmax[16];
#pragma unroll
    for (int oc = 0; oc < 16; ++oc) vmax[oc] = -1e30f;

    for (int p = t; p < 254; p += 64) {
        float c0 = ce[p], c1 = ce[p + 1], c2 = ce[p + 2];
#pragma unroll
        for (int oc = 0; oc < 16; ++oc) {
            float v = fmaf(c0, cwr[0][oc], fmaf(c1, cwr[1][oc], fmaf(c2, cwr[2][oc], cbr[oc])));
            vmax[oc] = fmaxf(vmax[oc], v);
        }
    }
#pragma unroll
    for (int m = 32; m; m >>= 1) {
#pragma unroll
        for (int oc = 0; oc < 16; ++oc)
            vmax[oc] = fmaxf(vmax[oc], __shfl_xor(vmax[oc], m));
    }
    if (t == 0) {
#pragma unroll
        for (int oc = 0; oc < 16; ++oc) {
            float v = vmax[oc];
            if (b != 0) v = fmaxf(v, 0.f);   // ref quirk: batch row 0 skips relu
            row[300 + oc] = f2b(v);
        }
    }
}

// ---------------------------------------------------------------------------
// Xg = X @ wih^T + (bih + bhh).  grid (48, 7, 2), block 256.
// gfx950: bf16 MFMA, 128x64 tile, BK=64.  Round-5/8/9 verified structure
// (double-buffered LDS, gload_lds A staging, source-side XOR swizzle,
// vectorized K-tail, tail MFMA trimmed to ceil(tail/32) steps).
// ---------------------------------------------------------------------------
#if defined(__gfx950__)

typedef __attribute__((ext_vector_type(4))) float f32x4;
typedef __attribute__((ext_vector_type(8))) __bf16 bf16x8;
#define LDPB 72  // Bs u16 pitch; 144 B = 9x16B rows, b128 reads 16B-aligned
#define BK   64

__device__ __forceinline__ void gload_lds16(const void* g, void* l) {
    __builtin_amdgcn_global_load_lds(
        (const __attribute__((address_space(1))) u32*)g,
        (__attribute__((address_space(3))) u32*)l, 16, 0, 0);
}

__global__ __launch_bounds__(256) void gemm_wih(
    const u16* __restrict__ px, const u16* __restrict__ hx,
    float* __restrict__ Xg_p, float* __restrict__ Xg_h,
    const void* __restrict__ wih, const void* __restrict__ bih,
    const void* __restrict__ bhh, int K, const int* __restrict__ flagp)
{
    const int bf = *flagp;
    const u16* A = blockIdx.z ? hx : px;
    float* C = blockIdx.z ? Xg_h : Xg_p;
    const int m0 = blockIdx.x * 128, n0 = blockIdx.y * 64;

    __shared__ __align__(16) u16 As0[128 * 64];   // unpadded, swizzled
    __shared__ __align__(16) u16 As1[128 * 64];
    __shared__ __align__(16) u16 Bs0[64 * LDPB];  // padded
    __shared__ __align__(16) u16 Bs1[64 * LDPB];

    const int tid  = threadIdx.x;
    const int lane = tid & 63;
    const int w    = tid >> 6;        // wave 0..3
    const int fr   = lane & 15;
    const int fq   = lane >> 4;

    // B staging: row rb, 32B chunk kb
    const int rb = tid >> 2;
    const int kb = (tid & 3) * 16;
    const int nB = n0 + rb;
    const int bok = nB < G_;

    // A async staging: wave w stages rows [w*32, w*32+32) in 4 calls of 8 rows.
    const int arow = lane >> 3;                 // 0..7
    const int achk = (lane & 7) ^ arow;         // logical chunk w/ swizzle
    const u16* aLane = A + (long)(m0 + w * 32 + arow) * PXP + achk * 8;

    const u16* wp = (const u16*)wih;
    const u16* bSrc = wp + (long)nB * K + kb;   // rows 8B-aligned (K%4==0)

    f32x4 acc[2][4] = {};

    auto loadB = [&](int k0, uint2* br4) {
        if (bok) {
            const u16* bp = bSrc + k0;
#pragma unroll
            for (int i = 0; i < 4; ++i) br4[i] = *(const uint2*)(bp + i * 4);
        } else {
#pragma unroll
            for (int i = 0; i < 4; ++i) { br4[i].x = 0u; br4[i].y = 0u; }
        }
    };
    auto stageA = [&](u16* dstAs, int k0) {
#pragma unroll
        for (int c = 0; c < 4; ++c)
            gload_lds16(aLane + (long)c * 8 * PXP + k0,
                        &dstAs[(w * 32 + c * 8) * 64]);
    };
    auto writeB = [&](u16* dstBs, const uint2* br4) {
        u16* bs = &dstBs[rb * LDPB + kb];
#pragma unroll
        for (int i = 0; i < 4; ++i) *(uint2*)(bs + i * 4) = br4[i];
    };
    auto compute = [&](const u16* As_, const u16* Bs_) {
#pragma unroll
        for (int ks = 0; ks < BK; ks += 32) {
            const int sw = (((ks >> 3) + fq) ^ (fr & 7)) * 8;  // swizzled read
            bf16x8 a0 = *(const bf16x8*)&As_[(w * 32 + fr) * 64 + sw];
            bf16x8 a1 = *(const bf16x8*)&As_[(w * 32 + 16 + fr) * 64 + sw];
#pragma unroll
            for (int j = 0; j < 4; ++j) {
                bf16x8 bj = *(const bf16x8*)&Bs_[(j * 16 + fr) * LDPB + ks + fq * 8];
                acc[0][j] = __builtin_amdgcn_mfma_f32_16x16x32_bf16(a0, bj, acc[0][j], 0, 0, 0);
                acc[1][j] = __builtin_amdgcn_mfma_f32_16x16x32_bf16(a1, bj, acc[1][j], 0, 0, 0);
            }
        }
    };

    const int nfull = K / BK;    // >= 4 for every layer

    // prologue: stage tile 0 into buf0
    {
        uint2 br4[4];
        loadB(0, br4);
        stageA(As0, 0);
        writeB(Bs0, br4);
    }
    asm volatile("s_waitcnt vmcnt(0) lgkmcnt(0)" ::: "memory");
    __builtin_amdgcn_s_barrier();

    int t = 0;
    while (t < nfull) {
        // phase 0: stage t+1 -> buf1, compute buf0
        if (t + 1 < nfull) {
            uint2 br4[4];
            loadB((t + 1) * BK, br4);
            stageA(As1, (t + 1) * BK);
            writeB(Bs1, br4);
        }
        compute(As0, Bs0);
        asm volatile("s_waitcnt vmcnt(0) lgkmcnt(0)" ::: "memory");
        __builtin_amdgcn_s_barrier();
        ++t;
        if (t >= nfull) break;

        // phase 1: stage t+1 -> buf0, compute buf1
        if (t + 1 < nfull) {
            uint2 br4[4];
            loadB((t + 1) * BK, br4);
            stageA(As0, (t + 1) * BK);
            writeB(Bs0, br4);
        }
        compute(As1, Bs1);
        asm volatile("s_waitcnt vmcnt(0) lgkmcnt(0)" ::: "memory");
        __builtin_amdgcn_s_barrier();
        ++t;
    }

    // K-tail (K % 64 in {60,4,12,20,28}): vectorized masked staging into buf0.
    const int k0 = nfull * BK;
    if (k0 < K) {
        {
            const int ra = tid >> 1;               // A row 0..127
            const int ka = (tid & 1) * 32;         // half-row offset in u16
            const u16* ar = A + (long)(m0 + ra) * PXP;
            const u16* br = wp + (long)nB * K;
            u16* bs = &Bs0[rb * LDPB + kb];
            // A: 8-u16 groups land in single swizzled 16B LDS chunks
#pragma unroll
            for (int c = 0; c < 4; ++c) {
                const int o0 = ka + c * 8;
                u16* dst = &As0[ra * 64 + (((o0 >> 3) ^ (ra & 7)) * 8)];
                if (k0 + o0 + 8 <= K) {
                    *(float4*)dst = *(const float4*)(ar + k0 + o0);
                } else {
#pragma unroll
                    for (int i = 0; i < 8; ++i) {
                        const int k = k0 + o0 + i;
                        dst[i] = (k < K) ? ar[k] : (u16)0;
                    }
                }
            }
            // B: 4-u16 groups (rows 8B-aligned)
#pragma unroll
            for (int c = 0; c < 4; ++c) {
                const int o0 = kb + c * 4;
                if (bok && k0 + o0 + 4 <= K) {
                    *(uint2*)(bs + o0 - kb) = *(const uint2*)(br + k0 + o0);
                } else {
#pragma unroll
                    for (int i = 0; i < 4; ++i) {
                        const int k = k0 + o0 + i;
                        bs[o0 - kb + i] = (bok && k < K) ? br[k] : (u16)0;
                    }
                }
            }
        }
        __syncthreads();
        // only ceil(tail/32) k-steps: staging zero-fills, skipped steps add +0
        const int ksend = ((K - k0 + 31) & ~31);
        for (int ks = 0; ks < ksend; ks += 32) {
            const int sw = (((ks >> 3) + fq) ^ (fr & 7)) * 8;
            bf16x8 a0 = *(const bf16x8*)&As0[(w * 32 + fr) * 64 + sw];
            bf16x8 a1 = *(const bf16x8*)&As0[(w * 32 + 16 + fr) * 64 + sw];
#pragma unroll
            for (int j = 0; j < 4; ++j) {
                bf16x8 bj = *(const bf16x8*)&Bs0[(j * 16 + fr) * LDPB + ks + fq * 8];
                acc[0][j] = __builtin_amdgcn_mfma_f32_16x16x32_bf16(a0, bj, acc[0][j], 0, 0, 0);
                acc[1][j] = __builtin_amdgcn_mfma_f32_16x16x32_bf16(a1, bj, acc[1][j], 0, 0, 0);
            }
        }
    }

    // D layout (m89-verified): lane holds D[row=fq*4+i][col=fr] per 16x16 tile
#pragma unroll
    for (int j = 0; j < 4; ++j) {
        const int col = n0 + j * 16 + fr;
        if (col < G_) {
            const float bias = ldw(bih, col, bf) + ldw(bhh, col, bf);
#pragma unroll
            for (int m = 0; m < 2; ++m)
#pragma unroll
                for (int i = 0; i < 4; ++i) {
                    const int row = m0 + w * 32 + m * 16 + fq * 4 + i;
                    C[(long)row * G_ + col] = acc[m][j][i] + bias;
                }
        }
    }
}
#undef LDPB
#undef BK

#else  // !__gfx950__ — vector fallback (never runs on gfx950)

__global__ __launch_bounds__(256) void gemm_wih(
    const u16* __restrict__ px, const u16* __restrict__ hx,
    float* __restrict__ Xg_p, float* __restrict__ Xg_h,
    const void* __restrict__ wih, const void* __restrict__ bih,
    const void* __restrict__ bhh, int K, const int* __restrict__ flagp)
{
    const int bf = *flagp;
    const u16* A = blockIdx.z ? hx : px;
    float* C = blockIdx.z ? Xg_h : Xg_p;

    __shared__ float As[16][64];
    __shared__ float Bs[16][64];

    const int tid = threadIdx.x;
    const int tx = tid & 15, ty = tid >> 4;
    const int m0 = blockIdx.x * 64, n0 = blockIdx.y * 64;
    const int lr = tid >> 2, lk = (tid & 3) * 4;

    float acc[4][4] = {};

    for (int k0 = 0; k0 < K; k0 += 16) {
        const u16* Ap = A + (long)(m0 + lr) * PXP + k0 + lk;
#pragma unroll
        for (int u = 0; u < 4; ++u)
            As[lk + u][lr] = (k0 + lk + u < K) ? b2f(Ap[u]) : 0.f;
        {
            const int n = n0 + lr;
#pragma unroll
            for (int u = 0; u < 4; ++u) {
                const int kk = k0 + lk + u;
                Bs[lk + u][lr] = (n < G_ && kk < K) ? ldw(wih, (long)n * K + kk, bf) : 0.f;
            }
        }
        __syncthreads();
#pragma unroll
        for (int k = 0; k < 16; ++k) {
            float a[4], bq[4];
#pragma unroll
            for (int i = 0; i < 4; ++i) a[i] = As[k][ty * 4 + i];
#pragma unroll
            for (int j = 0; j < 4; ++j) bq[j] = Bs[k][tx * 4 + j];
#pragma unroll
            for (int i = 0; i < 4; ++i)
#pragma unroll
                for (int j = 0; j < 4; ++j)
                    acc[i][j] = fmaf(a[i], bq[j], acc[i][j]);
        }
        __syncthreads();
    }

#pragma unroll
    for (int j = 0; j < 4; ++j) {
        const int col = n0 + tx * 4 + j;
        if (col < G_) {
            const float bias = ldw(bih, col, bf) + ldw(bhh, col, bf);
#pragma unroll
            for (int i = 0; i < 4; ++i)
                C[(long)(m0 + ty * 4 + i) * G_ + col] = acc[i][j] + bias;
        }
    }
}

#endif

// ---------------------------------------------------------------------------
// LSTM scan: one WG per (sample, sequence).  grid (128, 2), block 448.
// Weights held PACKED: 50 x u32 (2 bf16 each) per thread.  h broadcast via
// v_readlane (round-5 proven; round-7's ds_read broadcast was latency-bound,
// 74 us).  Barriers are lgkmcnt-only raw s_barrier: __syncthreads' implicit
// vmcnt(0) was draining the next-step Xg prefetch every step (T4 lesson --
// never drain vmcnt in the loop); the xg use's own waitcnt covers it.
// ---------------------------------------------------------------------------
__global__ __launch_bounds__(448, 2)
void lstm_scan(
    const float* __restrict__ Xg_p, const float* __restrict__ Xg_h,
    const void* __restrict__ whh,
    float* __restrict__ p_h, float* __restrict__ h_h,
    u16* __restrict__ px, u16* __restrict__ hx, int cat_off,
    const int* __restrict__ flagp)
{
    const int bf = *flagp;
    const int b = blockIdx.x, seq = blockIdx.y;
    const float* Xg = seq ? Xg_h : Xg_p;
    float* hout = seq ? h_h : p_h;
    u16* xcat = seq ? hx : px;
    const int g = threadIdx.x;
    const int l = g & 63;

    __shared__ float h_lds[128];             // h (100 used, padded)
    __shared__ float g_lds[400];             // gate pre-activations
    __shared__ float h_hist[S_ * 104];       // h history, flushed at end

    u32 wpk[50];                             // 50 packed bf16 pairs = row g of whh
    float xg = 0.f;
    if (g < G_) {
        if (bf) {
            const u32* w2 = (const u32*)whh;           // bf16 pairs, row-major
#pragma unroll
            for (int j = 0; j < 50; ++j) wpk[j] = w2[g * 50 + j];
        } else {
            const float* wf = (const float*)whh;       // legacy fp32 path
#pragma unroll
            for (int j = 0; j < 50; ++j) {
                u32 lo = f2b(wf[(long)g * 100 + 2 * j]);
                u32 hi = f2b(wf[(long)g * 100 + 2 * j + 1]);
                wpk[j] = lo | (hi << 16);
            }
        }
#pragma unroll
        for (int j = 0; j < 50; ++j) asm volatile("" : "+v"(wpk[j]));  // pin
        xg = Xg[(long)b * G_ + g];
    }
    if (g < 128) h_lds[g] = 0.f;
    float c_reg = 0.f;
    __syncthreads();

    for (int s = 0; s < S_; ++s) {
        // per-wave copy of h (2 LDS reads), broadcast via readlane below
        const float hv0 = h_lds[l];
        const float hv1 = h_lds[l + 64];
        if (g < G_) {
            float a0 = xg, a1 = 0.f, a2 = 0.f, a3 = 0.f;
#pragma unroll
            for (int u = 0; u < 100; u += 4) {
                const u32 p0 = wpk[u >> 1], p1 = wpk[(u >> 1) + 1];
                const float w0 = __int_as_float(p0 << 16);
                const float w1 = __int_as_float(p0 & 0xFFFF0000u);
                const float w2 = __int_as_float(p1 << 16);
                const float w3 = __int_as_float(p1 & 0xFFFF0000u);
                a0 = fmaf(rl(hv0, hv1, u),     w0, a0);
                a1 = fmaf(rl(hv0, hv1, u + 1), w1, a1);
                a2 = fmaf(rl(hv0, hv1, u + 2), w2, a2);
                a3 = fmaf(rl(hv0, hv1, u + 3), w3, a3);
            }
            g_lds[g] = (a0 + a1) + (a2 + a3);
            if (s + 1 < S_) xg = Xg[(long)((s + 1) * B_ + b) * G_ + g];  // prefetch
        }
        // barrier A: only g_lds visibility needed -> lgkm-only (xg load stays
        // in flight; its use-site waitcnt covers it next step)
        asm volatile("s_waitcnt lgkmcnt(0)" ::: "memory");
        __builtin_amdgcn_s_barrier();
        if (g < H_) {
            const float iv = fsig(g_lds[g]);
            const float fv = fsig(g_lds[100 + g]);
            const float gv = ftanh(g_lds[200 + g]);
            const float ov = fsig(g_lds[300 + g]);
            c_reg = fv * c_reg + iv * gv;
            const float hv = ov * ftanh(c_reg);
            h_lds[g] = hv;
            h_hist[s * 104 + g] = hv;
        }
        // barrier B: h_lds/h_hist visibility -> lgkm-only
        asm volatile("s_waitcnt lgkmcnt(0)" ::: "memory");
        __builtin_amdgcn_s_barrier();
    }

    // coalesced flush of the whole h history
    for (int i = g; i < S_ * H_; i += 448) {
        const int s = i / H_, d = i - s * H_;
        const float hv = h_hist[s * 104 + d];
        hout[(long)(s * B_ + b) * H_ + d] = hv;
        if (cat_off >= 0) xcat[(long)(s * B_ + b) * PXP + cat_off + d] = f2b(hv);
    }
}

// ---------------------------------------------------------------------------
// Cross attention.  grid (128, 2), block 256 — blockIdx.y picks direction.
// Softmax: exp computed once (stored during sum pass, scaled in place).
// ---------------------------------------------------------------------------
__global__ __launch_bounds__(256) void attn_kernel(
    const float* __restrict__ p_h, const float* __restrict__ h_h,
    u16* __restrict__ px, u16* __restrict__ hx, int off)
{
    const int b = blockIdx.x, dir = blockIdx.y, t = threadIdx.x;
    __shared__ __align__(16) float P[4800], Q[4800];
    __shared__ float A[2304], Sx[2304];

    {
        float4* P4 = (float4*)P;
        float4* Q4 = (float4*)Q;
        for (int i = t; i < 1200; i += 256) {
            const int s = i / 25, d4 = i % 25;
            P4[i] = *(const float4*)(p_h + (long)(s * B_ + b) * H_ + d4 * 4);
            Q4[i] = *(const float4*)(h_h + (long)(s * B_ + b) * H_ + d4 * 4);
        }
    }
    __syncthreads();

    for (int e = t; e < 2304; e += 256) {
        const int p = e / 48, q = e % 48;
        const float4* Pr = (const float4*)&P[p * 100];
        const float4* Qr = (const float4*)&Q[q * 100];
        float a0 = 0.f, a1 = 0.f;
#pragma unroll
        for (int j = 0; j < 25; ++j) {
            const float4 u = Pr[j], v = Qr[j];
            a0 = fmaf(u.x, v.x, a0); a1 = fmaf(u.y, v.y, a1);
            a0 = fmaf(u.z, v.z, a0); a1 = fmaf(u.w, v.w, a1);
        }
        A[e] = a0 + a1;
    }
    __syncthreads();

    if (t < 48) {
        if (dir == 0) {        // softmax over q for row t
            float m = -1e30f;
            for (int q = 0; q < 48; ++q) m = fmaxf(m, A[t * 48 + q]);
            float sum = 0.f;
            for (int q = 0; q < 48; ++q) {
                const float e = __expf(A[t * 48 + q] - m);
                Sx[t * 48 + q] = e;
                sum += e;
            }
            const float inv = 1.f / sum;
            for (int q = 0; q < 48; ++q) Sx[t * 48 + q] *= inv;
        } else {               // softmax over p for col t
            float m = -1e30f;
            for (int p = 0; p < 48; ++p) m = fmaxf(m, A[p * 48 + t]);
            float sum = 0.f;
            for (int p = 0; p < 48; ++p) {
                const float e = __expf(A[p * 48 + t] - m);
                Sx[p * 48 + t] = e;
                sum += e;
            }
            const float inv = 1.f / sum;
            for (int p = 0; p < 48; ++p) Sx[p * 48 + t] *= inv;
        }
    }
    __syncthreads();

    if (dir == 0) {
        for (int e = t; e < 4800; e += 256) {  // a_p = S @ Q
            const int p = e / 100, d = e % 100;
            float acc = 0.f;
            for (int q = 0; q < 48; ++q) acc = fmaf(Sx[p * 48 + q], Q[q * 100 + d], acc);
            px[(long)(p * B_ + b) * PXP + off + d] = f2b(acc);
        }
    } else {
        for (int e = t; e < 4800; e += 256) {  // a_h[q] = sum_p S2[p][q] * P[p]
            const int q = e / 100, d = e % 100;
            float acc = 0.f;
            for (int p = 0; p < 48; ++p) acc = fmaf(Sx[p * 48 + q], P[p * 100 + d], acc);
            hx[(long)(q * B_ + b) * PXP + off + d] = f2b(acc);
        }
    }
}

// ---------------------------------------------------------------------------
// Pool + feature build.  feats stored TRANSPOSED [500][128] so fcl's inner
// loop reads 512B-contiguous rows (bit-identical; layout only).
// ---------------------------------------------------------------------------
__global__ __launch_bounds__(256) void pool_feats(
    const float* __restrict__ p_h, const float* __restrict__ h_h,
    float* __restrict__ featsT)
{
    const int t = blockIdx.x * 256 + threadIdx.x;
    if (t >= B_ * H_) return;
    const int b = t / H_, u = t % H_;
    float hq = -1e30f, hs = -1e30f;
    for (int s = 0; s < S_; ++s) {
        hq = fmaxf(hq, p_h[(long)(s * B_ + b) * H_ + u]);
        hs = fmaxf(hs, h_h[(long)(s * B_ + b) * H_ + u]);
    }
    featsT[(      u) * B_ + b] = hq;
    featsT[(100 + u) * B_ + b] = hs;
    featsT[(200 + u) * B_ + b] = hs - hq;
    featsT[(300 + u) * B_ + b] = hq * hs;
    featsT[(400 + u) * B_ + b] = fabsf(hq - hs);
}

// ---------------------------------------------------------------------------
// z = relu(feats @ fcl_w^T + fcl_b).  featsT[d][b] reads coalesced;
// zT[o][b] writes coalesced.  Same math, same order -- bit-identical.
// ---------------------------------------------------------------------------
__global__ __launch_bounds__(256) void fcl_kernel(
    const float* __restrict__ featsT, const void* __restrict__ fw,
    const void* __restrict__ fb, float* __restrict__ zT, const int* __restrict__ flagp)
{
    const int bf = *flagp;
    const int t = blockIdx.x * 256 + threadIdx.x;
    const int o = t >> 7, b = t & 127;
    float acc = ldw(fb, o, bf);
    const long wrow = (long)o * 500;
    for (int d = 0; d < 500; ++d) acc = fmaf(featsT[d * B_ + b], ldw(fw, wrow + d, bf), acc);
    zT[o * B_ + b] = fmaxf(acc, 0.f);
}

// ---------------------------------------------------------------------------
// out = sigmoid(z @ last_w^T + last_b).  zT[o][b] reads coalesced (32
// distinct consecutive addrs/wave).  Output dtype follows flag.
// ---------------------------------------------------------------------------
__global__ __launch_bounds__(256) void last_kernel(
    const float* __restrict__ zT, const void* __restrict__ lw,
    const void* __restrict__ lb, void* __restrict__ out, const int* __restrict__ flagp)
{
    const int bf = *flagp;
    const int t = threadIdx.x;
    const int b = t >> 1, c = t & 1;
    float acc = ldw(lb, c, bf);
    for (int o = 0; o < 800; ++o) acc = fmaf(zT[o * B_ + b], ldw(lw, (long)c * 800 + o, bf), acc);
    const float v = 1.f / (1.f + expf(-acc));
    if (bf) ((u16*)out)[t] = f2b(v);
    else    ((float*)out)[t] = v;
}

// ---------------------------------------------------------------------------
extern "C" void kernel_launch(void* const* d_in, const int* in_sizes, int n_in,
                              void* d_out, int out_size, void* d_ws, size_t ws_size,
                              hipStream_t stream)
{
    (void)in_sizes; (void)n_in; (void)out_size; (void)ws_size;

    const int* qw = (const int*)d_in[0];
    const int* qc = (const int*)d_in[1];
    const int* sw = (const int*)d_in[2];
    const int* sc = (const int*)d_in[3];
    const void* wemb = d_in[4];
    const void* cemb = d_in[5];
    const void* cw   = d_in[6];
    const void* cb   = d_in[7];
    const void* fclw = d_in[28];
    const void* fclb = d_in[29];
    const void* lw   = d_in[30];
    const void* lb   = d_in[31];

    float* ws = (float*)d_ws;
    int*  flag = (int*)ws;                               // [16] floats reserved
    u16* px   = (u16*)(ws + 16);                         // bf16 px/hx
    u16* hx   = px + (long)S_ * B_ * PXP;
    float* Xg_p = (float*)(hx + (long)S_ * B_ * PXP);
    float* Xg_h = Xg_p + (long)S_ * B_ * G_;
    float* p_h  = Xg_h + (long)S_ * B_ * G_;
    float* h_h  = p_h + (long)S_ * B_ * H_;
    float* featsT = h_h + (long)S_ * B_ * H_;            // [500][128]
    float* zT   = featsT + 500 * B_;                     // [800][128]

    detect_kernel<<<dim3(1), 256, 0, stream>>>(wemb, flag);

    embed_kernel<<<dim3(B_, S_, 2), 64, 0, stream>>>(qw, qc, sw, sc, wemb, cemb, cw, cb, px, hx, flag);

    for (int k = 0; k < 5; ++k) {
        const void* wih = d_in[8 + 4 * k];
        const void* whh = d_in[9 + 4 * k];
        const void* bih = d_in[10 + 4 * k];
        const void* bhh = d_in[11 + 4 * k];
        const int K = 316 + 200 * k;

        gemm_wih<<<dim3(48, 7, 2), 256, 0, stream>>>(px, hx, Xg_p, Xg_h, wih, bih, bhh, K, flag);

        const int cat = (k < 4) ? (K + 100) : -1;
        lstm_scan<<<dim3(B_, 2), 448, 0, stream>>>(Xg_p, Xg_h, whh, p_h, h_h, px, hx, cat, flag);

        if (k < 4)
            attn_kernel<<<dim3(B_, 2), 256, 0, stream>>>(p_h, h_h, px, hx, K);
    }

    pool_feats<<<dim3(50), 256, 0, stream>>>(p_h, h_h, featsT);
    fcl_kernel<<<dim3(400), 256, 0, stream>>>(featsT, fclw, fclb, zT, flag);
    last_kernel<<<dim3(1), 256, 0, stream>>>(zT, lw, lb, d_out, flag);
}

// Round 11
// 788.876 us; speedup vs baseline: 1.3605x; 1.0782x over previous
//
#include <hip/hip_runtime.h>

typedef unsigned short u16;
typedef unsigned int   u32;

#define B_   128
#define S_   48
#define H_   100
#define G_   400
#define PXP  1120   // px/hx row pitch in u16 elements (1116 used, padded; 2240 B = 140x16B)

__device__ __forceinline__ float b2f(u16 u) {
    union { u32 i; float f; } v; v.i = ((u32)u) << 16; return v.f;
}
__device__ __forceinline__ u16 f2b(float f) {
    union { float f; u32 i; } v; v.f = f;
    u32 r = v.i + 0x7FFF + ((v.i >> 16) & 1);
    return (u16)(r >> 16);
}

// fast, overflow-safe activation forms (v_exp based; err ~1e-6 vs libm)
__device__ __forceinline__ float fsig(float x) { return 1.f / (1.f + __expf(-x)); }
__device__ __forceinline__ float ftanh(float x) {
    const float t = __expf(-2.f * fabsf(x));   // t in (0,1], no overflow
    const float r = (1.f - t) / (1.f + t);
    return copysignf(r, x);
}

// wave-uniform broadcast of h[u] held across two per-lane registers
__device__ __forceinline__ float rl(float v0, float v1, int u) {
    return __int_as_float(
        u < 64 ? __builtin_amdgcn_readlane(__float_as_int(v0), u)
               : __builtin_amdgcn_readlane(__float_as_int(v1), u - 64));
}

// dtype-flexible weight load: bf==1 -> bf16 storage, bf==0 -> fp32 storage
__device__ __forceinline__ float ldw(const void* p, long i, int bf) {
    return bf ? b2f(((const u16*)p)[i]) : ((const float*)p)[i];
}

// ---------------------------------------------------------------------------
// Dtype probe (proven in the passing runs).
// ---------------------------------------------------------------------------
__global__ __launch_bounds__(256) void detect_kernel(const void* wemb, int* flag)
{
    const int t = threadIdx.x;
    __shared__ int s;
    if (t == 0) s = 0;
    __syncthreads();
    int bad = 0;
    const u16* p = (const u16*)wemb;
    for (int i = t; i < 4096; i += 256) {
        float v = b2f(p[i]);
        if (!(fabsf(v) < 1e4f)) bad = 1;
    }
    if (bad) atomicOr(&s, 1);
    __syncthreads();
    if (t == 0) *flag = s ? 0 : 1;
}

// ---------------------------------------------------------------------------
// Embedding: word gather + char conv/maxpool.  grid (B, S, 2), block 64.
// ---------------------------------------------------------------------------
__global__ __launch_bounds__(64) void embed_kernel(
    const int* __restrict__ qw, const int* __restrict__ qc,
    const int* __restrict__ sw, const int* __restrict__ sc,
    const void* __restrict__ wemb, const void* __restrict__ cemb,
    const void* __restrict__ cw, const void* __restrict__ cb,
    u16* __restrict__ px, u16* __restrict__ hx, const int* __restrict__ flagp)
{
    const int bf = *flagp;
    const int b = blockIdx.x, s = blockIdx.y, seq = blockIdx.z;
    const int* words = seq ? sw : qw;
    const int* chars = seq ? sc : qc;
    u16* dst = seq ? hx : px;
    const int t = threadIdx.x;

    u16* row = dst + (long)(s * B_ + b) * PXP;
    const int w = words[b * S_ + s];
    if (bf) {
        const u32* src = (const u32*)((const u16*)wemb + (long)w * 300);
        u32* d32 = (u32*)row;
        for (int d = t; d < 150; d += 64) d32[d] = src[d];
    } else {
        const float* src = (const float*)wemb + (long)w * 300;
        for (int d = t; d < 300; d += 64) row[d] = f2b(src[d]);
    }

    __shared__ float ce[256];
    const int* ch = chars + (b * S_ + s) * 16;
    for (int j = t; j < 256; j += 64) {
        int ci = ch[j >> 4];
        ce[j] = ldw(cemb, ci * 16 + (j & 15), bf);
    }
    __syncthreads();

    float cwr[3][16], cbr[16];
#pragma unroll
    for (int oc = 0; oc < 16; ++oc) {
        cbr[oc] = ldw(cb, oc, bf);
#pragma unroll
        for (int kk = 0; kk < 3; ++kk) cwr[kk][oc] = ldw(cw, oc * 3 + kk, bf);
    }

    float vmax[16];
#pragma unroll
    for (int oc = 0; oc < 16; ++oc) vmax[oc] = -1e30f;

    for (int p = t; p < 254; p += 64) {
        float c0 = ce[p], c1 = ce[p + 1], c2 = ce[p + 2];
#pragma unroll
        for (int oc = 0; oc < 16; ++oc) {
            float v = fmaf(c0, cwr[0][oc], fmaf(c1, cwr[1][oc], fmaf(c2, cwr[2][oc], cbr[oc])));
            vmax[oc] = fmaxf(vmax[oc], v);
        }
    }
#pragma unroll
    for (int m = 32; m; m >>= 1) {
#pragma unroll
        for (int oc = 0; oc < 16; ++oc)
            vmax[oc] = fmaxf(vmax[oc], __shfl_xor(vmax[oc], m));
    }
    if (t == 0) {
#pragma unroll
        for (int oc = 0; oc < 16; ++oc) {
            float v = vmax[oc];
            if (b != 0) v = fmaxf(v, 0.f);   // ref quirk: batch row 0 skips relu
            row[300 + oc] = f2b(v);
        }
    }
}

// ---------------------------------------------------------------------------
// Xg = X @ wih^T + (bih + bhh).  grid (48, 7, 2), block 256.
// gfx950: bf16 MFMA, 128x64 tile, BK=64.  Round-5/8/9 verified structure
// (double-buffered LDS, gload_lds A staging, source-side XOR swizzle,
// vectorized K-tail, tail MFMA trimmed to ceil(tail/32) steps).
// ---------------------------------------------------------------------------
#if defined(__gfx950__)

typedef __attribute__((ext_vector_type(4))) float f32x4;
typedef __attribute__((ext_vector_type(8))) __bf16 bf16x8;
#define LDPB 72  // Bs u16 pitch; 144 B = 9x16B rows, b128 reads 16B-aligned
#define BK   64

__device__ __forceinline__ void gload_lds16(const void* g, void* l) {
    __builtin_amdgcn_global_load_lds(
        (const __attribute__((address_space(1))) u32*)g,
        (__attribute__((address_space(3))) u32*)l, 16, 0, 0);
}

__global__ __launch_bounds__(256) void gemm_wih(
    const u16* __restrict__ px, const u16* __restrict__ hx,
    float* __restrict__ Xg_p, float* __restrict__ Xg_h,
    const void* __restrict__ wih, const void* __restrict__ bih,
    const void* __restrict__ bhh, int K, const int* __restrict__ flagp)
{
    const int bf = *flagp;
    const u16* A = blockIdx.z ? hx : px;
    float* C = blockIdx.z ? Xg_h : Xg_p;
    const int m0 = blockIdx.x * 128, n0 = blockIdx.y * 64;

    __shared__ __align__(16) u16 As0[128 * 64];   // unpadded, swizzled
    __shared__ __align__(16) u16 As1[128 * 64];
    __shared__ __align__(16) u16 Bs0[64 * LDPB];  // padded
    __shared__ __align__(16) u16 Bs1[64 * LDPB];

    const int tid  = threadIdx.x;
    const int lane = tid & 63;
    const int w    = tid >> 6;        // wave 0..3
    const int fr   = lane & 15;
    const int fq   = lane >> 4;

    // B staging: row rb, 32B chunk kb
    const int rb = tid >> 2;
    const int kb = (tid & 3) * 16;
    const int nB = n0 + rb;
    const int bok = nB < G_;

    // A async staging: wave w stages rows [w*32, w*32+32) in 4 calls of 8 rows.
    const int arow = lane >> 3;                 // 0..7
    const int achk = (lane & 7) ^ arow;         // logical chunk w/ swizzle
    const u16* aLane = A + (long)(m0 + w * 32 + arow) * PXP + achk * 8;

    const u16* wp = (const u16*)wih;
    const u16* bSrc = wp + (long)nB * K + kb;   // rows 8B-aligned (K%4==0)

    f32x4 acc[2][4] = {};

    auto loadB = [&](int k0, uint2* br4) {
        if (bok) {
            const u16* bp = bSrc + k0;
#pragma unroll
            for (int i = 0; i < 4; ++i) br4[i] = *(const uint2*)(bp + i * 4);
        } else {
#pragma unroll
            for (int i = 0; i < 4; ++i) { br4[i].x = 0u; br4[i].y = 0u; }
        }
    };
    auto stageA = [&](u16* dstAs, int k0) {
#pragma unroll
        for (int c = 0; c < 4; ++c)
            gload_lds16(aLane + (long)c * 8 * PXP + k0,
                        &dstAs[(w * 32 + c * 8) * 64]);
    };
    auto writeB = [&](u16* dstBs, const uint2* br4) {
        u16* bs = &dstBs[rb * LDPB + kb];
#pragma unroll
        for (int i = 0; i < 4; ++i) *(uint2*)(bs + i * 4) = br4[i];
    };
    auto compute = [&](const u16* As_, const u16* Bs_) {
#pragma unroll
        for (int ks = 0; ks < BK; ks += 32) {
            const int sw = (((ks >> 3) + fq) ^ (fr & 7)) * 8;  // swizzled read
            bf16x8 a0 = *(const bf16x8*)&As_[(w * 32 + fr) * 64 + sw];
            bf16x8 a1 = *(const bf16x8*)&As_[(w * 32 + 16 + fr) * 64 + sw];
#pragma unroll
            for (int j = 0; j < 4; ++j) {
                bf16x8 bj = *(const bf16x8*)&Bs_[(j * 16 + fr) * LDPB + ks + fq * 8];
                acc[0][j] = __builtin_amdgcn_mfma_f32_16x16x32_bf16(a0, bj, acc[0][j], 0, 0, 0);
                acc[1][j] = __builtin_amdgcn_mfma_f32_16x16x32_bf16(a1, bj, acc[1][j], 0, 0, 0);
            }
        }
    };

    const int nfull = K / BK;    // >= 4 for every layer

    // prologue: stage tile 0 into buf0
    {
        uint2 br4[4];
        loadB(0, br4);
        stageA(As0, 0);
        writeB(Bs0, br4);
    }
    asm volatile("s_waitcnt vmcnt(0) lgkmcnt(0)" ::: "memory");
    __builtin_amdgcn_s_barrier();

    int t = 0;
    while (t < nfull) {
        // phase 0: stage t+1 -> buf1, compute buf0
        if (t + 1 < nfull) {
            uint2 br4[4];
            loadB((t + 1) * BK, br4);
            stageA(As1, (t + 1) * BK);
            writeB(Bs1, br4);
        }
        compute(As0, Bs0);
        asm volatile("s_waitcnt vmcnt(0) lgkmcnt(0)" ::: "memory");
        __builtin_amdgcn_s_barrier();
        ++t;
        if (t >= nfull) break;

        // phase 1: stage t+1 -> buf0, compute buf1
        if (t + 1 < nfull) {
            uint2 br4[4];
            loadB((t + 1) * BK, br4);
            stageA(As0, (t + 1) * BK);
            writeB(Bs0, br4);
        }
        compute(As1, Bs1);
        asm volatile("s_waitcnt vmcnt(0) lgkmcnt(0)" ::: "memory");
        __builtin_amdgcn_s_barrier();
        ++t;
    }

    // K-tail (K % 64 in {60,4,12,20,28}): vectorized masked staging into buf0.
    const int k0 = nfull * BK;
    if (k0 < K) {
        {
            const int ra = tid >> 1;               // A row 0..127
            const int ka = (tid & 1) * 32;         // half-row offset in u16
            const u16* ar = A + (long)(m0 + ra) * PXP;
            const u16* br = wp + (long)nB * K;
            u16* bs = &Bs0[rb * LDPB + kb];
            // A: 8-u16 groups land in single swizzled 16B LDS chunks
#pragma unroll
            for (int c = 0; c < 4; ++c) {
                const int o0 = ka + c * 8;
                u16* dst = &As0[ra * 64 + (((o0 >> 3) ^ (ra & 7)) * 8)];
                if (k0 + o0 + 8 <= K) {
                    *(float4*)dst = *(const float4*)(ar + k0 + o0);
                } else {
#pragma unroll
                    for (int i = 0; i < 8; ++i) {
                        const int k = k0 + o0 + i;
                        dst[i] = (k < K) ? ar[k] : (u16)0;
                    }
                }
            }
            // B: 4-u16 groups (rows 8B-aligned)
#pragma unroll
            for (int c = 0; c < 4; ++c) {
                const int o0 = kb + c * 4;
                if (bok && k0 + o0 + 4 <= K) {
                    *(uint2*)(bs + o0 - kb) = *(const uint2*)(br + k0 + o0);
                } else {
#pragma unroll
                    for (int i = 0; i < 4; ++i) {
                        const int k = k0 + o0 + i;
                        bs[o0 - kb + i] = (bok && k < K) ? br[k] : (u16)0;
                    }
                }
            }
        }
        __syncthreads();
        // only ceil(tail/32) k-steps: staging zero-fills, skipped steps add +0
        const int ksend = ((K - k0 + 31) & ~31);
        for (int ks = 0; ks < ksend; ks += 32) {
            const int sw = (((ks >> 3) + fq) ^ (fr & 7)) * 8;
            bf16x8 a0 = *(const bf16x8*)&As0[(w * 32 + fr) * 64 + sw];
            bf16x8 a1 = *(const bf16x8*)&As0[(w * 32 + 16 + fr) * 64 + sw];
#pragma unroll
            for (int j = 0; j < 4; ++j) {
                bf16x8 bj = *(const bf16x8*)&Bs0[(j * 16 + fr) * LDPB + ks + fq * 8];
                acc[0][j] = __builtin_amdgcn_mfma_f32_16x16x32_bf16(a0, bj, acc[0][j], 0, 0, 0);
                acc[1][j] = __builtin_amdgcn_mfma_f32_16x16x32_bf16(a1, bj, acc[1][j], 0, 0, 0);
            }
        }
    }

    // D layout (m89-verified): lane holds D[row=fq*4+i][col=fr] per 16x16 tile
#pragma unroll
    for (int j = 0; j < 4; ++j) {
        const int col = n0 + j * 16 + fr;
        if (col < G_) {
            const float bias = ldw(bih, col, bf) + ldw(bhh, col, bf);
#pragma unroll
            for (int m = 0; m < 2; ++m)
#pragma unroll
                for (int i = 0; i < 4; ++i) {
                    const int row = m0 + w * 32 + m * 16 + fq * 4 + i;
                    C[(long)row * G_ + col] = acc[m][j][i] + bias;
                }
        }
    }
}
#undef LDPB
#undef BK

#else  // !__gfx950__ — vector fallback (never runs on gfx950)

__global__ __launch_bounds__(256) void gemm_wih(
    const u16* __restrict__ px, const u16* __restrict__ hx,
    float* __restrict__ Xg_p, float* __restrict__ Xg_h,
    const void* __restrict__ wih, const void* __restrict__ bih,
    const void* __restrict__ bhh, int K, const int* __restrict__ flagp)
{
    const int bf = *flagp;
    const u16* A = blockIdx.z ? hx : px;
    float* C = blockIdx.z ? Xg_h : Xg_p;

    __shared__ float As[16][64];
    __shared__ float Bs[16][64];

    const int tid = threadIdx.x;
    const int tx = tid & 15, ty = tid >> 4;
    const int m0 = blockIdx.x * 64, n0 = blockIdx.y * 64;
    const int lr = tid >> 2, lk = (tid & 3) * 4;

    float acc[4][4] = {};

    for (int k0 = 0; k0 < K; k0 += 16) {
        const u16* Ap = A + (long)(m0 + lr) * PXP + k0 + lk;
#pragma unroll
        for (int u = 0; u < 4; ++u)
            As[lk + u][lr] = (k0 + lk + u < K) ? b2f(Ap[u]) : 0.f;
        {
            const int n = n0 + lr;
#pragma unroll
            for (int u = 0; u < 4; ++u) {
                const int kk = k0 + lk + u;
                Bs[lk + u][lr] = (n < G_ && kk < K) ? ldw(wih, (long)n * K + kk, bf) : 0.f;
            }
        }
        __syncthreads();
#pragma unroll
        for (int k = 0; k < 16; ++k) {
            float a[4], bq[4];
#pragma unroll
            for (int i = 0; i < 4; ++i) a[i] = As[k][ty * 4 + i];
#pragma unroll
            for (int j = 0; j < 4; ++j) bq[j] = Bs[k][tx * 4 + j];
#pragma unroll
            for (int i = 0; i < 4; ++i)
#pragma unroll
                for (int j = 0; j < 4; ++j)
                    acc[i][j] = fmaf(a[i], bq[j], acc[i][j]);
        }
        __syncthreads();
    }

#pragma unroll
    for (int j = 0; j < 4; ++j) {
        const int col = n0 + tx * 4 + j;
        if (col < G_) {
            const float bias = ldw(bih, col, bf) + ldw(bhh, col, bf);
#pragma unroll
            for (int i = 0; i < 4; ++i)
                C[(long)(m0 + ty * 4 + i) * G_ + col] = acc[i][j] + bias;
        }
    }
}

#endif

// ---------------------------------------------------------------------------
// LSTM scan: one WG per (sample, sequence).  grid (128, 2), block 448.
// Weights held PACKED: 50 x u32 (2 bf16 each) per thread.  h broadcast via
// v_readlane (round-5 proven; round-7's ds_read broadcast was latency-bound,
// 74 us).  Barriers are lgkmcnt-only raw s_barrier: __syncthreads' implicit
// vmcnt(0) was draining the next-step Xg prefetch every step (T4 lesson --
// never drain vmcnt in the loop); the xg use's own waitcnt covers it.
// ---------------------------------------------------------------------------
__global__ __launch_bounds__(448, 2)
void lstm_scan(
    const float* __restrict__ Xg_p, const float* __restrict__ Xg_h,
    const void* __restrict__ whh,
    float* __restrict__ p_h, float* __restrict__ h_h,
    u16* __restrict__ px, u16* __restrict__ hx, int cat_off,
    const int* __restrict__ flagp)
{
    const int bf = *flagp;
    const int b = blockIdx.x, seq = blockIdx.y;
    const float* Xg = seq ? Xg_h : Xg_p;
    float* hout = seq ? h_h : p_h;
    u16* xcat = seq ? hx : px;
    const int g = threadIdx.x;
    const int l = g & 63;

    __shared__ float h_lds[128];             // h (100 used, padded)
    __shared__ float g_lds[400];             // gate pre-activations
    __shared__ float h_hist[S_ * 104];       // h history, flushed at end

    u32 wpk[50];                             // 50 packed bf16 pairs = row g of whh
    float xg = 0.f;
    if (g < G_) {
        if (bf) {
            const u32* w2 = (const u32*)whh;           // bf16 pairs, row-major
#pragma unroll
            for (int j = 0; j < 50; ++j) wpk[j] = w2[g * 50 + j];
        } else {
            const float* wf = (const float*)whh;       // legacy fp32 path
#pragma unroll
            for (int j = 0; j < 50; ++j) {
                u32 lo = f2b(wf[(long)g * 100 + 2 * j]);
                u32 hi = f2b(wf[(long)g * 100 + 2 * j + 1]);
                wpk[j] = lo | (hi << 16);
            }
        }
#pragma unroll
        for (int j = 0; j < 50; ++j) asm volatile("" : "+v"(wpk[j]));  // pin
        xg = Xg[(long)b * G_ + g];
    }
    if (g < 128) h_lds[g] = 0.f;
    float c_reg = 0.f;
    __syncthreads();

    for (int s = 0; s < S_; ++s) {
        // per-wave copy of h (2 LDS reads), broadcast via readlane below
        const float hv0 = h_lds[l];
        const float hv1 = h_lds[l + 64];
        if (g < G_) {
            float a0 = xg, a1 = 0.f, a2 = 0.f, a3 = 0.f;
#pragma unroll
            for (int u = 0; u < 100; u += 4) {
                const u32 p0 = wpk[u >> 1], p1 = wpk[(u >> 1) + 1];
                const float w0 = __int_as_float(p0 << 16);
                const float w1 = __int_as_float(p0 & 0xFFFF0000u);
                const float w2 = __int_as_float(p1 << 16);
                const float w3 = __int_as_float(p1 & 0xFFFF0000u);
                a0 = fmaf(rl(hv0, hv1, u),     w0, a0);
                a1 = fmaf(rl(hv0, hv1, u + 1), w1, a1);
                a2 = fmaf(rl(hv0, hv1, u + 2), w2, a2);
                a3 = fmaf(rl(hv0, hv1, u + 3), w3, a3);
            }
            g_lds[g] = (a0 + a1) + (a2 + a3);
            if (s + 1 < S_) xg = Xg[(long)((s + 1) * B_ + b) * G_ + g];  // prefetch
        }
        // barrier A: only g_lds visibility needed -> lgkm-only (xg load stays
        // in flight; its use-site waitcnt covers it next step)
        asm volatile("s_waitcnt lgkmcnt(0)" ::: "memory");
        __builtin_amdgcn_s_barrier();
        if (g < H_) {
            const float iv = fsig(g_lds[g]);
            const float fv = fsig(g_lds[100 + g]);
            const float gv = ftanh(g_lds[200 + g]);
            const float ov = fsig(g_lds[300 + g]);
            c_reg = fv * c_reg + iv * gv;
            const float hv = ov * ftanh(c_reg);
            h_lds[g] = hv;
            h_hist[s * 104 + g] = hv;
        }
        // barrier B: h_lds/h_hist visibility -> lgkm-only
        asm volatile("s_waitcnt lgkmcnt(0)" ::: "memory");
        __builtin_amdgcn_s_barrier();
    }

    // coalesced flush of the whole h history
    for (int i = g; i < S_ * H_; i += 448) {
        const int s = i / H_, d = i - s * H_;
        const float hv = h_hist[s * 104 + d];
        hout[(long)(s * B_ + b) * H_ + d] = hv;
        if (cat_off >= 0) xcat[(long)(s * B_ + b) * PXP + cat_off + d] = f2b(hv);
    }
}

// ---------------------------------------------------------------------------
// Cross attention.  grid (128, 2), block 256 — blockIdx.y picks direction.
// Softmax: exp computed once (stored during sum pass, scaled in place).
// ---------------------------------------------------------------------------
__global__ __launch_bounds__(256) void attn_kernel(
    const float* __restrict__ p_h, const float* __restrict__ h_h,
    u16* __restrict__ px, u16* __restrict__ hx, int off)
{
    const int b = blockIdx.x, dir = blockIdx.y, t = threadIdx.x;
    __shared__ __align__(16) float P[4800], Q[4800];
    __shared__ float A[2304], Sx[2304];

    {
        float4* P4 = (float4*)P;
        float4* Q4 = (float4*)Q;
        for (int i = t; i < 1200; i += 256) {
            const int s = i / 25, d4 = i % 25;
            P4[i] = *(const float4*)(p_h + (long)(s * B_ + b) * H_ + d4 * 4);
            Q4[i] = *(const float4*)(h_h + (long)(s * B_ + b) * H_ + d4 * 4);
        }
    }
    __syncthreads();

    for (int e = t; e < 2304; e += 256) {
        const int p = e / 48, q = e % 48;
        const float4* Pr = (const float4*)&P[p * 100];
        const float4* Qr = (const float4*)&Q[q * 100];
        float a0 = 0.f, a1 = 0.f;
#pragma unroll
        for (int j = 0; j < 25; ++j) {
            const float4 u = Pr[j], v = Qr[j];
            a0 = fmaf(u.x, v.x, a0); a1 = fmaf(u.y, v.y, a1);
            a0 = fmaf(u.z, v.z, a0); a1 = fmaf(u.w, v.w, a1);
        }
        A[e] = a0 + a1;
    }
    __syncthreads();

    if (t < 48) {
        if (dir == 0) {        // softmax over q for row t
            float m = -1e30f;
            for (int q = 0; q < 48; ++q) m = fmaxf(m, A[t * 48 + q]);
            float sum = 0.f;
            for (int q = 0; q < 48; ++q) {
                const float e = __expf(A[t * 48 + q] - m);
                Sx[t * 48 + q] = e;
                sum += e;
            }
            const float inv = 1.f / sum;
            for (int q = 0; q < 48; ++q) Sx[t * 48 + q] *= inv;
        } else {               // softmax over p for col t
            float m = -1e30f;
            for (int p = 0; p < 48; ++p) m = fmaxf(m, A[p * 48 + t]);
            float sum = 0.f;
            for (int p = 0; p < 48; ++p) {
                const float e = __expf(A[p * 48 + t] - m);
                Sx[p * 48 + t] = e;
                sum += e;
            }
            const float inv = 1.f / sum;
            for (int p = 0; p < 48; ++p) Sx[p * 48 + t] *= inv;
        }
    }
    __syncthreads();

    if (dir == 0) {
        for (int e = t; e < 4800; e += 256) {  // a_p = S @ Q
            const int p = e / 100, d = e % 100;
            float acc = 0.f;
            for (int q = 0; q < 48; ++q) acc = fmaf(Sx[p * 48 + q], Q[q * 100 + d], acc);
            px[(long)(p * B_ + b) * PXP + off + d] = f2b(acc);
        }
    } else {
        for (int e = t; e < 4800; e += 256) {  // a_h[q] = sum_p S2[p][q] * P[p]
            const int q = e / 100, d = e % 100;
            float acc = 0.f;
            for (int p = 0; p < 48; ++p) acc = fmaf(Sx[p * 48 + q], P[p * 100 + d], acc);
            hx[(long)(q * B_ + b) * PXP + off + d] = f2b(acc);
        }
    }
}

// ---------------------------------------------------------------------------
// Pool + feature build.  feats stored TRANSPOSED [500][128] so fcl's inner
// loop reads 512B-contiguous rows (bit-identical; layout only).
// ---------------------------------------------------------------------------
__global__ __launch_bounds__(256) void pool_feats(
    const float* __restrict__ p_h, const float* __restrict__ h_h,
    float* __restrict__ featsT)
{
    const int t = blockIdx.x * 256 + threadIdx.x;
    if (t >= B_ * H_) return;
    const int b = t / H_, u = t % H_;
    float hq = -1e30f, hs = -1e30f;
    for (int s = 0; s < S_; ++s) {
        hq = fmaxf(hq, p_h[(long)(s * B_ + b) * H_ + u]);
        hs = fmaxf(hs, h_h[(long)(s * B_ + b) * H_ + u]);
    }
    featsT[(      u) * B_ + b] = hq;
    featsT[(100 + u) * B_ + b] = hs;
    featsT[(200 + u) * B_ + b] = hs - hq;
    featsT[(300 + u) * B_ + b] = hq * hs;
    featsT[(400 + u) * B_ + b] = fabsf(hq - hs);
}

// ---------------------------------------------------------------------------
// z = relu(feats @ fcl_w^T + fcl_b).  featsT[d][b] reads coalesced;
// zT[o][b] writes coalesced.  Same math, same order -- bit-identical.
// ---------------------------------------------------------------------------
__global__ __launch_bounds__(256) void fcl_kernel(
    const float* __restrict__ featsT, const void* __restrict__ fw,
    const void* __restrict__ fb, float* __restrict__ zT, const int* __restrict__ flagp)
{
    const int bf = *flagp;
    const int t = blockIdx.x * 256 + threadIdx.x;
    const int o = t >> 7, b = t & 127;
    float acc = ldw(fb, o, bf);
    const long wrow = (long)o * 500;
    for (int d = 0; d < 500; ++d) acc = fmaf(featsT[d * B_ + b], ldw(fw, wrow + d, bf), acc);
    zT[o * B_ + b] = fmaxf(acc, 0.f);
}

// ---------------------------------------------------------------------------
// out = sigmoid(z @ last_w^T + last_b).  grid (128), block 256 -- one block
// per sample (round-10 profile: single-block version was 70 us, latency-bound
// at 0.04% occupancy with HBM-miss serialization).  Each 128-thread c-group
// strides the 800-dot; shuffle+LDS reduce (round-6-proven reduction shape,
// reassociation noise << bf16 output quantum).
// ---------------------------------------------------------------------------
__global__ __launch_bounds__(256) void last_kernel(
    const float* __restrict__ zT, const void* __restrict__ lw,
    const void* __restrict__ lb, void* __restrict__ out, const int* __restrict__ flagp)
{
    const int bf = *flagp;
    const int b = blockIdx.x, t = threadIdx.x;
    const int c = t >> 7;          // 0 or 1
    const int u = t & 127;
    __shared__ float red[4];

    float part = 0.f;
    for (int o = u; o < 800; o += 128)
        part = fmaf(zT[o * B_ + b], ldw(lw, (long)c * 800 + o, bf), part);
#pragma unroll
    for (int m = 32; m; m >>= 1) part += __shfl_xor(part, m);
    if ((t & 63) == 0) red[t >> 6] = part;   // per-wave partials
    __syncthreads();
    if (t < 2) {
        const float acc = red[2 * t] + red[2 * t + 1] + ldw(lb, t, bf);
        const float v = 1.f / (1.f + expf(-acc));
        if (bf) ((u16*)out)[b * 2 + t] = f2b(v);
        else    ((float*)out)[b * 2 + t] = v;
    }
}

// ---------------------------------------------------------------------------
extern "C" void kernel_launch(void* const* d_in, const int* in_sizes, int n_in,
                              void* d_out, int out_size, void* d_ws, size_t ws_size,
                              hipStream_t stream)
{
    (void)in_sizes; (void)n_in; (void)out_size; (void)ws_size;

    const int* qw = (const int*)d_in[0];
    const int* qc = (const int*)d_in[1];
    const int* sw = (const int*)d_in[2];
    const int* sc = (const int*)d_in[3];
    const void* wemb = d_in[4];
    const void* cemb = d_in[5];
    const void* cw   = d_in[6];
    const void* cb   = d_in[7];
    const void* fclw = d_in[28];
    const void* fclb = d_in[29];
    const void* lw   = d_in[30];
    const void* lb   = d_in[31];

    float* ws = (float*)d_ws;
    int*  flag = (int*)ws;                               // [16] floats reserved
    u16* px   = (u16*)(ws + 16);                         // bf16 px/hx
    u16* hx   = px + (long)S_ * B_ * PXP;
    float* Xg_p = (float*)(hx + (long)S_ * B_ * PXP);
    float* Xg_h = Xg_p + (long)S_ * B_ * G_;
    float* p_h  = Xg_h + (long)S_ * B_ * G_;
    float* h_h  = p_h + (long)S_ * B_ * H_;
    float* featsT = h_h + (long)S_ * B_ * H_;            // [500][128]
    float* zT   = featsT + 500 * B_;                     // [800][128]

    detect_kernel<<<dim3(1), 256, 0, stream>>>(wemb, flag);

    embed_kernel<<<dim3(B_, S_, 2), 64, 0, stream>>>(qw, qc, sw, sc, wemb, cemb, cw, cb, px, hx, flag);

    for (int k = 0; k < 5; ++k) {
        const void* wih = d_in[8 + 4 * k];
        const void* whh = d_in[9 + 4 * k];
        const void* bih = d_in[10 + 4 * k];
        const void* bhh = d_in[11 + 4 * k];
        const int K = 316 + 200 * k;

        gemm_wih<<<dim3(48, 7, 2), 256, 0, stream>>>(px, hx, Xg_p, Xg_h, wih, bih, bhh, K, flag);

        const int cat = (k < 4) ? (K + 100) : -1;
        lstm_scan<<<dim3(B_, 2), 448, 0, stream>>>(Xg_p, Xg_h, whh, p_h, h_h, px, hx, cat, flag);

        if (k < 4)
            attn_kernel<<<dim3(B_, 2), 256, 0, stream>>>(p_h, h_h, px, hx, K);
    }

    pool_feats<<<dim3(50), 256, 0, stream>>>(p_h, h_h, featsT);
    fcl_kernel<<<dim3(400), 256, 0, stream>>>(featsT, fclw, fclb, zT, flag);
    last_kernel<<<dim3(B_), 256, 0, stream>>>(zT, lw, lb, d_out, flag);
}